// Round 9
// baseline (188.252 us; speedup 1.0000x reference)
//
#include <hip/hip_runtime.h>
#include <math.h>

// Problem constants (AttentionLikeModel_75531294867774)
#define DIMM    1024
#define NHEADS  16
#define HDIM    64
#define BATCH   2
#define SEQ     2048
#define ROWS    (BATCH*SEQ)   // 4096

typedef _Float16 f16x8 __attribute__((ext_vector_type(8)));
typedef _Float16 f16x4 __attribute__((ext_vector_type(4)));
typedef float    f32x4 __attribute__((ext_vector_type(4)));
typedef float    f32x16 __attribute__((ext_vector_type(16)));

__device__ inline void gl_lds16(const void* g, void* l) {
    __builtin_amdgcn_global_load_lds(
        (const __attribute__((address_space(1))) void*)g,
        (__attribute__((address_space(3))) void*)l, 16, 0, 0);
}

static __device__ inline f16x8 mkfrag(unsigned a, unsigned b, unsigned c, unsigned d) {
    union { unsigned u[4]; f16x8 v; } x;
    x.u[0] = a; x.u[1] = b; x.u[2] = c; x.u[3] = d;
    return x.v;
}

// ---------------------------------------------------------------------------
// Merged prep: blocks [0,2048) cvt x -> fp16; [2048,2816) W_qkv^T; [2816,3072) W_out^T
// ---------------------------------------------------------------------------
__device__ void tcvt64(const float* __restrict__ in, _Float16* __restrict__ out,
                       int K, int N, int k0, int n0, float (*tile)[65], int t)
{
    {
        const int c4 = (t & 15) * 4;
        const int r  = t >> 4;
        #pragma unroll
        for (int i = 0; i < 4; i++) {
            const int rr = r + 16 * i;
            float4 v = *(const float4*)(in + (size_t)(k0 + rr) * N + n0 + c4);
            tile[rr][c4] = v.x; tile[rr][c4 + 1] = v.y;
            tile[rr][c4 + 2] = v.z; tile[rr][c4 + 3] = v.w;
        }
    }
    __syncthreads();
    #pragma unroll
    for (int i = 0; i < 2; i++) {
        const int seg = t + 256 * i;
        const int n   = seg >> 3;
        const int kc  = (seg & 7) * 8;
        f16x8 o;
        #pragma unroll
        for (int j = 0; j < 8; j++) o[j] = (_Float16)tile[kc + j][n];
        *(f16x8*)(out + (size_t)(n0 + n) * K + k0 + kc) = o;
    }
}

__global__ __launch_bounds__(256)
void prep_kernel(const float* __restrict__ x, const float* __restrict__ Wqkv,
                 const float* __restrict__ Wout, _Float16* __restrict__ xh,
                 _Float16* __restrict__ wqkvt, _Float16* __restrict__ woutt)
{
    __shared__ float tile[64][65];
    const int bx = blockIdx.x;
    const int t  = threadIdx.x;
    if (bx < 2048) {                       // cvt x (4096x1024 / 8 / 256 = 2048 blocks)
        const int i = bx * 256 + t;
        const float4 a = *(const float4*)(x + (size_t)i * 8);
        const float4 b = *(const float4*)(x + (size_t)i * 8 + 4);
        f16x8 o;
        o[0] = (_Float16)a.x; o[1] = (_Float16)a.y; o[2] = (_Float16)a.z; o[3] = (_Float16)a.w;
        o[4] = (_Float16)b.x; o[5] = (_Float16)b.y; o[6] = (_Float16)b.z; o[7] = (_Float16)b.w;
        *(f16x8*)(xh + (size_t)i * 8) = o;
    } else if (bx < 2816) {                // W_qkv^T: grid (48,16)
        const int id = bx - 2048;
        const int gx = id % 48, gy = id / 48;
        tcvt64(Wqkv, wqkvt, DIMM, 3 * DIMM, gy * 64, gx * 64, tile, t);
    } else {                               // W_out^T: grid (16,16)
        const int id = bx - 2816;
        const int gx = id & 15, gy = id >> 4;
        tcvt64(Wout, woutt, DIMM, DIMM, gy * 64, gx * 64, tile, t);
    }
}

// ---------------------------------------------------------------------------
// qkv HGEMM 256x256, 8 waves (512 thr), 32x32x16 MFMA. One __syncthreads per
// K-iter (race-free-by-construction dbuf). V-third staged through LDS and
// written to vtg[bh][d][key] as contiguous 128B runs. UNCHANGED from round 8.
// ---------------------------------------------------------------------------
__global__ __launch_bounds__(512)
void hgemm256_kernel(const _Float16* __restrict__ A, const _Float16* __restrict__ Bt,
                     const float* __restrict__ bias, _Float16* __restrict__ C,
                     _Float16* __restrict__ vtg, int N, int K)
{
    __shared__ __align__(16) _Float16 lds[65536];   // 128 KB

    const int t    = threadIdx.x;
    const int w    = t >> 6, lane = t & 63;
    const int l31  = lane & 31;
    const int hf   = lane >> 5;
    const int l7   = lane & 7;
    const int wm   = w >> 2;            // 0..1 -> m-offset wm*128
    const int wn   = w & 3;             // 0..3 -> n-offset wn*64
    const int row0 = blockIdx.y * 256, col0 = blockIdx.x * 256;

    f32x16 acc[4][2];
    #pragma unroll
    for (int mi = 0; mi < 4; mi++)
        #pragma unroll
        for (int ni = 0; ni < 2; ni++)
            #pragma unroll
            for (int r = 0; r < 16; r++) acc[mi][ni][r] = 0.f;

    const _Float16* gA[4];
    const _Float16* gB[4];
    int sofs[4];
    #pragma unroll
    for (int j = 0; j < 4; j++) {
        const int s   = t + 512 * j;
        const int row = s >> 3;
        const int kb  = (s & 7) ^ (row & 7);
        gA[j] = A  + (size_t)(row0 + row) * K + kb * 8;
        gB[j] = Bt + (size_t)(col0 + row) * K + kb * 8;
        sofs[j] = s * 8;
    }

    #pragma unroll
    for (int j = 0; j < 4; j++) gl_lds16(gA[j], lds + sofs[j]);
    #pragma unroll
    for (int j = 0; j < 4; j++) gl_lds16(gB[j], lds + 32768 + sofs[j]);
    #pragma unroll
    for (int j = 0; j < 4; j++) { gA[j] += 64; gB[j] += 64; }

    const int niter = K >> 6;   // 16
    #pragma unroll 1
    for (int it = 0; it < niter; it++) {
        const int cur = it & 1;
        __syncthreads();

        if (it + 1 < niter) {
            const int nxt = cur ^ 1;
            #pragma unroll
            for (int j = 0; j < 4; j++) gl_lds16(gA[j], lds + nxt * 16384 + sofs[j]);
            #pragma unroll
            for (int j = 0; j < 4; j++) gl_lds16(gB[j], lds + 32768 + nxt * 16384 + sofs[j]);
            #pragma unroll
            for (int j = 0; j < 4; j++) { gA[j] += 64; gB[j] += 64; }
        }

        const _Float16* AsC = lds + cur * 16384;
        const _Float16* BsC = lds + 32768 + cur * 16384;
        #pragma unroll
        for (int ks = 0; ks < 4; ks++) {
            const int pseg = ((ks * 2 + hf) ^ l7) * 8;
            f16x8 bf0 = *(const f16x8*)(BsC + (wn * 64 +      l31) * 64 + pseg);
            f16x8 bf1 = *(const f16x8*)(BsC + (wn * 64 + 32 + l31) * 64 + pseg);
            #pragma unroll
            for (int mi = 0; mi < 4; mi++) {
                f16x8 af = *(const f16x8*)(AsC + (wm * 128 + mi * 32 + l31) * 64 + pseg);
                acc[mi][0] = __builtin_amdgcn_mfma_f32_32x32x16_f16(af, bf0, acc[mi][0], 0, 0, 0);
                acc[mi][1] = __builtin_amdgcn_mfma_f32_32x32x16_f16(af, bf1, acc[mi][1], 0, 0, 0);
            }
        }
    }

    float bv[2];
    #pragma unroll
    for (int ni = 0; ni < 2; ni++) bv[ni] = bias[col0 + wn * 64 + ni * 32 + l31];

    if (blockIdx.x < 8) {
        #pragma unroll
        for (int mi = 0; mi < 4; mi++)
            #pragma unroll
            for (int ni = 0; ni < 2; ni++) {
                const int col = col0 + wn * 64 + ni * 32 + l31;
                #pragma unroll
                for (int r = 0; r < 16; r++) {
                    const int row = row0 + wm * 128 + mi * 32 + (r & 3) + 8 * (r >> 2) + 4 * hf;
                    C[(size_t)row * N + col] = (_Float16)(acc[mi][ni][r] + bv[ni]);
                }
            }
        return;
    }

    // V third: transpose via LDS -> vtg[bh][d][key], coalesced 128B runs.
    __syncthreads();
    #pragma unroll
    for (int mi = 0; mi < 4; mi++)
        #pragma unroll
        for (int ni = 0; ni < 2; ni++) {
            const int coll = wn * 64 + ni * 32 + l31;
            #pragma unroll
            for (int rq = 0; rq < 4; rq++) {
                f16x4 o;
                #pragma unroll
                for (int ri = 0; ri < 4; ri++) o[ri] = (_Float16)(acc[mi][ni][rq * 4 + ri] + bv[ni]);
                const int sidx = rq + 4 * mi + 16 * wm;          // 16B seg along key
                *(f16x4*)(lds + coll * 256 + ((sidx ^ (coll & 31)) << 3) + 4 * hf) = o;
            }
        }
    __syncthreads();
    {
        const int cl   = t >> 1;            // col_local 0..255
        const int half = t & 1;             // key half 0/1
        const int head = ((blockIdx.x - 8) << 2) + (cl >> 6);
        const int dv   = cl & 63;
        const int bb   = blockIdx.y >> 3;   // batch
        const int key0 = (blockIdx.y & 7) * 256 + half * 128;
        _Float16* dst = vtg + ((size_t)(bb * 16 + head) * 64 + dv) * SEQ + key0;
        #pragma unroll
        for (int c = 0; c < 16; c++) {
            const int cs = half * 16 + c;   // 16B seg along key, 0..31
            *(f16x8*)(dst + c * 8) = *(const f16x8*)(lds + cl * 256 + ((cs ^ (cl & 31)) << 3));
        }
    }
}

// ---------------------------------------------------------------------------
// out-GEMM: 64x128 dbuf pipelined, one __syncthreads per iter. UNCHANGED.
// ---------------------------------------------------------------------------
__global__ __launch_bounds__(256)
void hgemm_out_kernel(const _Float16* __restrict__ A, const _Float16* __restrict__ Bt,
                      const float* __restrict__ bias, float* __restrict__ Cout,
                      int N, int K)
{
    constexpr int BM = 64, MI = 2;
    __shared__ _Float16 As[2][BM * 64];
    __shared__ _Float16 Bs[2][128 * 64];

    const int t    = threadIdx.x;
    const int w    = t >> 6, lane = t & 63;
    const int quad = lane >> 4, l16 = lane & 15;
    const int wr   = w >> 1, wc = w & 1;
    const int row0 = blockIdx.y * BM, col0 = blockIdx.x * 128;
    const int sw   = l16 & 7;

    f32x4 acc[MI][4];
    #pragma unroll
    for (int i = 0; i < MI; i++)
        #pragma unroll
        for (int j = 0; j < 4; j++)
            #pragma unroll
            for (int r = 0; r < 4; r++) acc[i][j][r] = 0.f;

    const _Float16* gA[MI];
    int aofs[MI];
    #pragma unroll
    for (int j = 0; j < MI; j++) {
        const int s   = t + 256 * j;
        const int row = s >> 3;
        const int kb  = (s & 7) ^ (row & 7);
        gA[j] = A + (size_t)(row0 + row) * K + kb * 8;
        aofs[j] = s * 8;
    }
    const _Float16* gB[4];
    int bofs[4];
    #pragma unroll
    for (int j = 0; j < 4; j++) {
        const int s   = t + 256 * j;
        const int row = s >> 3;
        const int kb  = (s & 7) ^ (row & 7);
        gB[j] = Bt + (size_t)(col0 + row) * K + kb * 8;
        bofs[j] = s * 8;
    }

    #pragma unroll
    for (int j = 0; j < MI; j++) gl_lds16(gA[j], &As[0][aofs[j]]);
    #pragma unroll
    for (int j = 0; j < 4; j++)  gl_lds16(gB[j], &Bs[0][bofs[j]]);
    #pragma unroll
    for (int j = 0; j < MI; j++) gA[j] += 64;
    #pragma unroll
    for (int j = 0; j < 4; j++)  gB[j] += 64;

    const int niter = K >> 6;
    #pragma unroll 1
    for (int it = 0; it < niter; it++) {
        const int cur = it & 1;
        __syncthreads();

        if (it + 1 < niter) {
            const int nxt = cur ^ 1;
            #pragma unroll
            for (int j = 0; j < MI; j++) gl_lds16(gA[j], &As[nxt][aofs[j]]);
            #pragma unroll
            for (int j = 0; j < 4; j++)  gl_lds16(gB[j], &Bs[nxt][bofs[j]]);
            #pragma unroll
            for (int j = 0; j < MI; j++) gA[j] += 64;
            #pragma unroll
            for (int j = 0; j < 4; j++)  gB[j] += 64;
        }

        const _Float16* AsC = &As[cur][0];
        const _Float16* BsC = &Bs[cur][0];
        f16x8 af[MI][2], bf[4][2];
        #pragma unroll
        for (int i = 0; i < MI; i++) {
            const int arow = wr * (BM / 2) + i * 16 + l16;
            #pragma unroll
            for (int hh = 0; hh < 2; hh++)
                af[i][hh] = *(const f16x8*)(AsC + (arow * 8 + ((hh * 4 + quad) ^ sw)) * 8);
        }
        #pragma unroll
        for (int j = 0; j < 4; j++) {
            const int brow = wc * 64 + j * 16 + l16;
            #pragma unroll
            for (int hh = 0; hh < 2; hh++)
                bf[j][hh] = *(const f16x8*)(BsC + (brow * 8 + ((hh * 4 + quad) ^ sw)) * 8);
        }
        #pragma unroll
        for (int i = 0; i < MI; i++)
            #pragma unroll
            for (int j = 0; j < 4; j++) {
                acc[i][j] = __builtin_amdgcn_mfma_f32_16x16x32_f16(af[i][0], bf[j][0], acc[i][j], 0, 0, 0);
                acc[i][j] = __builtin_amdgcn_mfma_f32_16x16x32_f16(af[i][1], bf[j][1], acc[i][j], 0, 0, 0);
            }
    }

    #pragma unroll
    for (int j = 0; j < 4; j++) {
        const int col = col0 + wc * 64 + j * 16 + l16;
        const float bv = bias[col];
        #pragma unroll
        for (int i = 0; i < MI; i++) {
            const int row = row0 + wr * (BM / 2) + i * 16 + quad * 4;
            #pragma unroll
            for (int r = 0; r < 4; r++)
                Cout[(size_t)(row + r) * N + col] = acc[i][j][r] + bv;
        }
    }
}

// ---------------------------------------------------------------------------
// MFMA flash attention — in-register P (32x32x16), ONE __syncthreads per
// tile. Round-9 changes (all flash-local, sync structure untouched):
//  (a) exp chain 2-mul -> 1-mul: 2^(s * 0.125*log2e) via raw v_exp_f32
//      (ISA: D = 2^S0; VALU, HW-interlocked). Saves 16 v_mul/tile/lane.
//  (b) T5: s_setprio(1) around QK and PV MFMA clusters (attn-proven m191;
//      prerequisite holds: no mid-tile barrier -> waves in different phases).
//  (c) XCD-clustered bijective block swizzle: all 32 same-bh blocks (which
//      share K/V) land on one XCD (4 bh/XCD, 2 MB <= 4 MB L2). Pure
//      relabeling of (qt,bh) -> correctness-independent. Diagnostic:
//      FETCH_SIZE should drop ~70 -> ~35-45 MB.
// ---------------------------------------------------------------------------
__global__ __launch_bounds__(256, 4)
void flash_attn_kernel(const _Float16* __restrict__ qkv,
                       const _Float16* __restrict__ vtg,
                       _Float16* __restrict__ out)
{
    // (c) XCD swizzle: lin -> (qt, bh); same-bh blocks are 8 apart in
    // dispatch order -> same XCD under round-robin block->XCD assignment.
    const int lin = blockIdx.y * 32 + blockIdx.x;   // 0..1023
    const int bh  = (lin & 7) * 4 + (lin >> 8);     // 0..31
    const int qt  = (lin >> 3) & 31;                // 0..31
    const int b  = bh >> 4, hd = bh & 15;
    const int t    = threadIdx.x;
    const int w    = t >> 6;
    const int lane = t & 63;
    const int qg   = w >> 1;            // q-group (32 rows)
    const int kh   = w & 1;             // key-half (32 keys)
    const int l31  = lane & 31;
    const int hf   = lane >> 5;         // lane half
    const int l7   = lane & 7;

    __shared__ __align__(16) _Float16 Ks [2][64 * 64];
    __shared__ __align__(16) _Float16 Vts[2][64 * 64];

    const int q0 = qt * 64;
    const size_t rstr = 3 * DIMM;
    const _Float16* qbase = qkv + (size_t)b * SEQ * rstr;

    f16x8 qf[4];
    {
        const _Float16* qrow = qbase + (size_t)(q0 + qg * 32 + l31) * rstr + hd * HDIM;
        #pragma unroll
        for (int dd = 0; dd < 4; dd++)
            qf[dd] = *(const f16x8*)(qrow + dd * 16 + hf * 8);
    }

    f32x16 Oacc[2];
    #pragma unroll
    for (int dh = 0; dh < 2; dh++)
        #pragma unroll
        for (int r = 0; r < 16; r++) Oacc[dh][r] = 0.f;
    float lrow = 0.f;

    const int seg0 = t, seg1 = t + 256;
    const int r0 = seg0 >> 3, lb0 = (seg0 & 7) ^ (r0 & 7);
    const int r1 = seg1 >> 3, lb1 = (seg1 & 7) ^ (r1 & 7);
    const _Float16* gK0 = qbase + (size_t)r0 * rstr + DIMM + hd * HDIM + lb0 * 8;
    const _Float16* gK1 = qbase + (size_t)r1 * rstr + DIMM + hd * HDIM + lb1 * 8;
    const _Float16* gV0 = vtg + ((size_t)bh * 64 + r0) * SEQ + lb0 * 8;
    const _Float16* gV1 = vtg + ((size_t)bh * 64 + r1) * SEQ + lb1 * 8;

    gl_lds16(gK0, &Ks [0][seg0 * 8]);
    gl_lds16(gK1, &Ks [0][seg1 * 8]);
    gl_lds16(gV0, &Vts[0][seg0 * 8]);
    gl_lds16(gV1, &Vts[0][seg1 * 8]);

    #pragma unroll 2
    for (int k0 = 0; k0 < SEQ; k0 += 64) {
        const int cur = (k0 >> 6) & 1;
        const _Float16* KsC  = &Ks [cur][0];
        const _Float16* VtsC = &Vts[cur][0];

        __syncthreads();

        f32x16 sacc;
        #pragma unroll
        for (int r = 0; r < 16; r++) sacc[r] = 0.f;
        __builtin_amdgcn_s_setprio(1);
        #pragma unroll
        for (int dd = 0; dd < 4; dd++) {
            f16x8 kf = *(const f16x8*)(KsC + (kh * 32 + l31) * 64 + (((dd * 2 + hf) ^ l7) * 8));
            sacc = __builtin_amdgcn_mfma_f32_32x32x16_f16(kf, qf[dd], sacc, 0, 0, 0);
        }
        __builtin_amdgcn_s_setprio(0);

        if (k0 + 64 < SEQ) {
            const int nxt = cur ^ 1;
            gl_lds16(gK0 + (size_t)(k0 + 64) * rstr, &Ks [nxt][seg0 * 8]);
            gl_lds16(gK1 + (size_t)(k0 + 64) * rstr, &Ks [nxt][seg1 * 8]);
            gl_lds16(gV0 + (k0 + 64),                &Vts[nxt][seg0 * 8]);
            gl_lds16(gV1 + (k0 + 64),                &Vts[nxt][seg1 * 8]);
        }

        // (a) e = 2^(s * 0.125*log2e) — one mul + v_exp_f32 per element
        float e[16];
        #pragma unroll
        for (int r = 0; r < 16; r++) {
            const float xx = sacc[r] * 0.18033688011112042f;   // 0.125*log2(e)
            float ee;
            asm("v_exp_f32 %0, %1" : "=v"(ee) : "v"(xx));
            e[r] = ee;
            lrow += ee;
        }

        unsigned w01 = __builtin_bit_cast(unsigned, __builtin_amdgcn_cvt_pkrtz(e[0],  e[1]));
        unsigned w23 = __builtin_bit_cast(unsigned, __builtin_amdgcn_cvt_pkrtz(e[2],  e[3]));
        unsigned w45 = __builtin_bit_cast(unsigned, __builtin_amdgcn_cvt_pkrtz(e[4],  e[5]));
        unsigned w67 = __builtin_bit_cast(unsigned, __builtin_amdgcn_cvt_pkrtz(e[6],  e[7]));
        unsigned w89 = __builtin_bit_cast(unsigned, __builtin_amdgcn_cvt_pkrtz(e[8],  e[9]));
        unsigned wab = __builtin_bit_cast(unsigned, __builtin_amdgcn_cvt_pkrtz(e[10], e[11]));
        unsigned wcd = __builtin_bit_cast(unsigned, __builtin_amdgcn_cvt_pkrtz(e[12], e[13]));
        unsigned wef = __builtin_bit_cast(unsigned, __builtin_amdgcn_cvt_pkrtz(e[14], e[15]));
        unsigned p00 = w01, p02 = w45;
        asm("v_permlane32_swap_b32 %0, %1" : "+v"(p00), "+v"(p02));
        unsigned p01 = w23, p03 = w67;
        asm("v_permlane32_swap_b32 %0, %1" : "+v"(p01), "+v"(p03));
        unsigned p10 = w89, p12 = wcd;
        asm("v_permlane32_swap_b32 %0, %1" : "+v"(p10), "+v"(p12));
        unsigned p11 = wab, p13 = wef;
        asm("v_permlane32_swap_b32 %0, %1" : "+v"(p11), "+v"(p13));
        f16x8 pa0 = mkfrag(p00, p01, p02, p03);
        f16x8 pa1 = mkfrag(p10, p11, p12, p13);

        __builtin_amdgcn_s_setprio(1);
        #pragma unroll
        for (int dh = 0; dh < 2; dh++) {
            const _Float16* vrow = VtsC + (dh * 32 + l31) * 64;
            f16x8 vf0 = *(const f16x8*)(vrow + (((kh * 4 + 0 + hf) ^ l7) * 8));
            f16x8 vf1 = *(const f16x8*)(vrow + (((kh * 4 + 2 + hf) ^ l7) * 8));
            Oacc[dh] = __builtin_amdgcn_mfma_f32_32x32x16_f16(pa0, vf0, Oacc[dh], 0, 0, 0);
            Oacc[dh] = __builtin_amdgcn_mfma_f32_32x32x16_f16(pa1, vf1, Oacc[dh], 0, 0, 0);
        }
        __builtin_amdgcn_s_setprio(0);
    }

    float lsum = lrow + __shfl_xor(lrow, 32);
    __syncthreads();
    float* Obuf = (float*)&Ks[0][0];
    float* lbuf = (float*)&Vts[0][0];
    if (kh) {
        #pragma unroll
        for (int dh = 0; dh < 2; dh++)
            #pragma unroll
            for (int r = 0; r < 16; r++) {
                const int q = (r & 3) + 8 * (r >> 2) + 4 * hf;
                Obuf[(qg * 32 + q) * 64 + dh * 32 + l31] = Oacc[dh][r];
            }
        if (lane < 32) lbuf[qg * 32 + lane] = lsum;
    }
    __syncthreads();
    if (!kh) {
        const float dnrec = 1.f / (lsum + lbuf[qg * 32 + l31]);
        float dq[16];
        #pragma unroll
        for (int r = 0; r < 16; r++)
            dq[r] = __shfl(dnrec, (r & 3) + 8 * (r >> 2) + 4 * hf);
        #pragma unroll
        for (int dh = 0; dh < 2; dh++)
            #pragma unroll
            for (int r = 0; r < 16; r++) {
                const int q = (r & 3) + 8 * (r >> 2) + 4 * hf;
                const float v = (Oacc[dh][r] + Obuf[(qg * 32 + q) * 64 + dh * 32 + l31])
                                * dq[r];
                out[(size_t)(b * SEQ + q0 + qg * 32 + q) * DIMM + hd * HDIM + dh * 32 + l31] =
                    (_Float16)v;
            }
    }
}

// ---------------------------------------------------------------------------
extern "C" void kernel_launch(void* const* d_in, const int* in_sizes, int n_in,
                              void* d_out, int out_size, void* d_ws, size_t ws_size,
                              hipStream_t stream)
{
    const float* x    = (const float*)d_in[0];   // [2,2048,1024]
    const float* Wqkv = (const float*)d_in[1];   // [1024,3072]
    const float* bqkv = (const float*)d_in[2];   // [3072]
    const float* Wout = (const float*)d_in[3];   // [1024,1024]
    const float* bout = (const float*)d_in[4];   // [1024]
    float* out = (float*)d_out;                  // [2,2048,1024]

    _Float16* qkvh  = (_Float16*)d_ws;                   // 4096x3072 (V-third unused)
    _Float16* attnh = qkvh  + (size_t)ROWS * 3 * DIMM;   // 4096x1024
    _Float16* xh    = attnh + (size_t)ROWS * DIMM;       // 4096x1024
    _Float16* wqkvt = xh    + (size_t)ROWS * DIMM;       // 3072x1024
    _Float16* woutt = wqkvt + (size_t)3 * DIMM * DIMM;   // 1024x1024
    _Float16* vtg   = woutt + (size_t)DIMM * DIMM;       // 32 x 64 x 2048

    // 0) merged fp16 conversions (x, W_qkv^T, W_out^T)
    prep_kernel<<<3072, 256, 0, stream>>>(x, Wqkv, Wout, xh, wqkvt, woutt);
    // 1) qkv = x @ W_qkv + b_qkv (fp16); V-third -> vtg transposed. 256x256 tiles.
    {
        dim3 grid(3 * DIMM / 256, ROWS / 256);   // (12,16)
        hgemm256_kernel<<<grid, 512, 0, stream>>>(xh, wqkvt, bqkv, qkvh, vtg, 3 * DIMM, DIMM);
    }
    // 2) attention -> attnh (fp16)
    {
        dim3 grid(SEQ / 64, BATCH * NHEADS);
        flash_attn_kernel<<<grid, 256, 0, stream>>>(qkvh, vtg, attnh);
    }
    // 3) out = attn @ W_out + b_out (fp32) — 64x128 dbuf, 512 blocks
    {
        dim3 grid(DIMM / 128, ROWS / 64);
        hgemm_out_kernel<<<grid, 256, 0, stream>>>(attnh, woutt, bout, out, DIMM, DIMM);
    }
}

// Round 10
// 187.155 us; speedup vs baseline: 1.0059x; 1.0059x over previous
//
#include <hip/hip_runtime.h>
#include <math.h>

// Problem constants (AttentionLikeModel_75531294867774)
#define DIMM    1024
#define NHEADS  16
#define HDIM    64
#define BATCH   2
#define SEQ     2048
#define ROWS    (BATCH*SEQ)   // 4096

typedef _Float16 f16x8 __attribute__((ext_vector_type(8)));
typedef _Float16 f16x4 __attribute__((ext_vector_type(4)));
typedef _Float16 h2    __attribute__((ext_vector_type(2)));
typedef float    f32x4 __attribute__((ext_vector_type(4)));
typedef float    f32x16 __attribute__((ext_vector_type(16)));

__device__ inline void gl_lds16(const void* g, void* l) {
    __builtin_amdgcn_global_load_lds(
        (const __attribute__((address_space(1))) void*)g,
        (__attribute__((address_space(3))) void*)l, 16, 0, 0);
}

static __device__ inline f16x8 mkfrag(unsigned a, unsigned b, unsigned c, unsigned d) {
    union { unsigned u[4]; f16x8 v; } x;
    x.u[0] = a; x.u[1] = b; x.u[2] = c; x.u[3] = d;
    return x.v;
}
static __device__ inline f16x8 cvt8(const float4& a, const float4& b) {
    unsigned u0 = __builtin_bit_cast(unsigned, __builtin_amdgcn_cvt_pkrtz(a.x, a.y));
    unsigned u1 = __builtin_bit_cast(unsigned, __builtin_amdgcn_cvt_pkrtz(a.z, a.w));
    unsigned u2 = __builtin_bit_cast(unsigned, __builtin_amdgcn_cvt_pkrtz(b.x, b.y));
    unsigned u3 = __builtin_bit_cast(unsigned, __builtin_amdgcn_cvt_pkrtz(b.z, b.w));
    return mkfrag(u0, u1, u2, u3);
}

// ---------------------------------------------------------------------------
// Prep (weights only now): blocks [0,768) W_qkv^T; [768,1024) W_out^T.
// x conversion is fused into the qkv GEMM (A reg-staged f32 -> f16).
// ---------------------------------------------------------------------------
__device__ void tcvt64(const float* __restrict__ in, _Float16* __restrict__ out,
                       int K, int N, int k0, int n0, float (*tile)[65], int t)
{
    {
        const int c4 = (t & 15) * 4;
        const int r  = t >> 4;
        #pragma unroll
        for (int i = 0; i < 4; i++) {
            const int rr = r + 16 * i;
            float4 v = *(const float4*)(in + (size_t)(k0 + rr) * N + n0 + c4);
            tile[rr][c4] = v.x; tile[rr][c4 + 1] = v.y;
            tile[rr][c4 + 2] = v.z; tile[rr][c4 + 3] = v.w;
        }
    }
    __syncthreads();
    #pragma unroll
    for (int i = 0; i < 2; i++) {
        const int seg = t + 256 * i;
        const int n   = seg >> 3;
        const int kc  = (seg & 7) * 8;
        f16x8 o;
        #pragma unroll
        for (int j = 0; j < 8; j++) o[j] = (_Float16)tile[kc + j][n];
        *(f16x8*)(out + (size_t)(n0 + n) * K + k0 + kc) = o;
    }
}

__global__ __launch_bounds__(256)
void prep_kernel(const float* __restrict__ Wqkv, const float* __restrict__ Wout,
                 _Float16* __restrict__ wqkvt, _Float16* __restrict__ woutt)
{
    __shared__ float tile[64][65];
    const int bx = blockIdx.x;
    const int t  = threadIdx.x;
    if (bx < 768) {                        // W_qkv^T: grid (48,16)
        const int gx = bx % 48, gy = bx / 48;
        tcvt64(Wqkv, wqkvt, DIMM, 3 * DIMM, gy * 64, gx * 64, tile, t);
    } else {                               // W_out^T: grid (16,16)
        const int id = bx - 768;
        const int gx = id & 15, gy = id >> 4;
        tcvt64(Wout, woutt, DIMM, DIMM, gy * 64, gx * 64, tile, t);
    }
}

// ---------------------------------------------------------------------------
// qkv HGEMM 256x256, 8 waves (512 thr), 32x32x16 MFMA, A = x in f32 (fused
// conversion): A is reg-staged (8 dwordx4 -> cvt_pkrtz -> 4 ds_write_b128),
// B DMA'd via global_load_lds. Race-free-by-construction: ONE __syncthreads
// per K-iter; ALL iter-t LDS writes (A ds_writes + B DMAs) target buf[nxt],
// all fragment reads target buf[cur]; barrier drains lgkm+vmcnt.
// A loads issued right after the barrier (latency hides under MFMA phase);
// A ds_writes after the MFMA phase. V-third epilogue unchanged from R8.
// ---------------------------------------------------------------------------
__global__ __launch_bounds__(512)
void hgemm256_kernel(const float* __restrict__ X, const _Float16* __restrict__ Bt,
                     const float* __restrict__ bias, _Float16* __restrict__ C,
                     _Float16* __restrict__ vtg, int N, int K)
{
    __shared__ __align__(16) _Float16 lds[65536];   // 128 KB

    const int t    = threadIdx.x;
    const int w    = t >> 6, lane = t & 63;
    const int l31  = lane & 31;
    const int hf   = lane >> 5;
    const int l7   = lane & 7;
    const int wm   = w >> 2;            // 0..1 -> m-offset wm*128
    const int wn   = w & 3;             // 0..3 -> n-offset wn*64
    const int row0 = blockIdx.y * 256, col0 = blockIdx.x * 256;

    f32x16 acc[4][2];
    #pragma unroll
    for (int mi = 0; mi < 4; mi++)
        #pragma unroll
        for (int ni = 0; ni < 2; ni++)
            #pragma unroll
            for (int r = 0; r < 16; r++) acc[mi][ni][r] = 0.f;

    const float*    gAf[4];
    const _Float16* gB[4];
    int sofs[4];
    #pragma unroll
    for (int j = 0; j < 4; j++) {
        const int s   = t + 512 * j;
        const int row = s >> 3;
        const int kb  = (s & 7) ^ (row & 7);
        gAf[j] = X  + (size_t)(row0 + row) * K + kb * 8;   // f32 source
        gB[j]  = Bt + (size_t)(col0 + row) * K + kb * 8;
        sofs[j] = s * 8;
    }

    // prologue: stage tile 0 into buffer 0 (A via regs, B via DMA)
    {
        float4 pa[4], pb[4];
        #pragma unroll
        for (int j = 0; j < 4; j++) {
            pa[j] = *(const float4*)(gAf[j]);
            pb[j] = *(const float4*)(gAf[j] + 4);
        }
        #pragma unroll
        for (int j = 0; j < 4; j++) *(f16x8*)(lds + sofs[j]) = cvt8(pa[j], pb[j]);
        #pragma unroll
        for (int j = 0; j < 4; j++) gl_lds16(gB[j], lds + 32768 + sofs[j]);
        #pragma unroll
        for (int j = 0; j < 4; j++) { gAf[j] += 64; gB[j] += 64; }
    }

    const int niter = K >> 6;   // 16
    #pragma unroll 1
    for (int it = 0; it < niter; it++) {
        const int cur = it & 1;
        __syncthreads();        // drains buf[cur] A-writes + B-DMAs; joins buf[cur^1] reads

        float4 pa[4], pb[4];
        const int nxt = cur ^ 1;
        if (it + 1 < niter) {
            #pragma unroll
            for (int j = 0; j < 4; j++) {          // A loads for t+1 (regs)
                pa[j] = *(const float4*)(gAf[j]);
                pb[j] = *(const float4*)(gAf[j] + 4);
            }
            #pragma unroll
            for (int j = 0; j < 4; j++)            // B DMA for t+1
                gl_lds16(gB[j], lds + 32768 + nxt * 16384 + sofs[j]);
            #pragma unroll
            for (int j = 0; j < 4; j++) { gAf[j] += 64; gB[j] += 64; }
        }

        const _Float16* AsC = lds + cur * 16384;
        const _Float16* BsC = lds + 32768 + cur * 16384;
        #pragma unroll
        for (int ks = 0; ks < 4; ks++) {
            const int pseg = ((ks * 2 + hf) ^ l7) * 8;
            f16x8 bf0 = *(const f16x8*)(BsC + (wn * 64 +      l31) * 64 + pseg);
            f16x8 bf1 = *(const f16x8*)(BsC + (wn * 64 + 32 + l31) * 64 + pseg);
            #pragma unroll
            for (int mi = 0; mi < 4; mi++) {
                f16x8 af = *(const f16x8*)(AsC + (wm * 128 + mi * 32 + l31) * 64 + pseg);
                acc[mi][0] = __builtin_amdgcn_mfma_f32_32x32x16_f16(af, bf0, acc[mi][0], 0, 0, 0);
                acc[mi][1] = __builtin_amdgcn_mfma_f32_32x32x16_f16(af, bf1, acc[mi][1], 0, 0, 0);
            }
        }

        if (it + 1 < niter) {
            #pragma unroll
            for (int j = 0; j < 4; j++)            // A ds_write into buf[nxt]
                *(f16x8*)(lds + nxt * 16384 + sofs[j]) = cvt8(pa[j], pb[j]);
        }
    }

    float bv[2];
    #pragma unroll
    for (int ni = 0; ni < 2; ni++) bv[ni] = bias[col0 + wn * 64 + ni * 32 + l31];

    if (blockIdx.x < 8) {
        #pragma unroll
        for (int mi = 0; mi < 4; mi++)
            #pragma unroll
            for (int ni = 0; ni < 2; ni++) {
                const int col = col0 + wn * 64 + ni * 32 + l31;
                #pragma unroll
                for (int r = 0; r < 16; r++) {
                    const int row = row0 + wm * 128 + mi * 32 + (r & 3) + 8 * (r >> 2) + 4 * hf;
                    C[(size_t)row * N + col] = (_Float16)(acc[mi][ni][r] + bv[ni]);
                }
            }
        return;
    }

    // V third: transpose via LDS -> vtg[bh][d][key], coalesced 128B runs.
    __syncthreads();
    #pragma unroll
    for (int mi = 0; mi < 4; mi++)
        #pragma unroll
        for (int ni = 0; ni < 2; ni++) {
            const int coll = wn * 64 + ni * 32 + l31;
            #pragma unroll
            for (int rq = 0; rq < 4; rq++) {
                f16x4 o;
                #pragma unroll
                for (int ri = 0; ri < 4; ri++) o[ri] = (_Float16)(acc[mi][ni][rq * 4 + ri] + bv[ni]);
                const int sidx = rq + 4 * mi + 16 * wm;          // 16B seg along key
                *(f16x4*)(lds + coll * 256 + ((sidx ^ (coll & 31)) << 3) + 4 * hf) = o;
            }
        }
    __syncthreads();
    {
        const int cl   = t >> 1;            // col_local 0..255
        const int half = t & 1;             // key half 0/1
        const int head = ((blockIdx.x - 8) << 2) + (cl >> 6);
        const int dv   = cl & 63;
        const int bb   = blockIdx.y >> 3;   // batch
        const int key0 = (blockIdx.y & 7) * 256 + half * 128;
        _Float16* dst = vtg + ((size_t)(bb * 16 + head) * 64 + dv) * SEQ + key0;
        #pragma unroll
        for (int c = 0; c < 16; c++) {
            const int cs = half * 16 + c;   // 16B seg along key, 0..31
            *(f16x8*)(dst + c * 8) = *(const f16x8*)(lds + cl * 256 + ((cs ^ (cl & 31)) << 3));
        }
    }
}

// ---------------------------------------------------------------------------
// out-GEMM: 64x128 dbuf pipelined, one __syncthreads per iter. UNCHANGED.
// ---------------------------------------------------------------------------
__global__ __launch_bounds__(256)
void hgemm_out_kernel(const _Float16* __restrict__ A, const _Float16* __restrict__ Bt,
                      const float* __restrict__ bias, float* __restrict__ Cout,
                      int N, int K)
{
    constexpr int BM = 64, MI = 2;
    __shared__ _Float16 As[2][BM * 64];
    __shared__ _Float16 Bs[2][128 * 64];

    const int t    = threadIdx.x;
    const int w    = t >> 6, lane = t & 63;
    const int quad = lane >> 4, l16 = lane & 15;
    const int wr   = w >> 1, wc = w & 1;
    const int row0 = blockIdx.y * BM, col0 = blockIdx.x * 128;
    const int sw   = l16 & 7;

    f32x4 acc[MI][4];
    #pragma unroll
    for (int i = 0; i < MI; i++)
        #pragma unroll
        for (int j = 0; j < 4; j++)
            #pragma unroll
            for (int r = 0; r < 4; r++) acc[i][j][r] = 0.f;

    const _Float16* gA[MI];
    int aofs[MI];
    #pragma unroll
    for (int j = 0; j < MI; j++) {
        const int s   = t + 256 * j;
        const int row = s >> 3;
        const int kb  = (s & 7) ^ (row & 7);
        gA[j] = A + (size_t)(row0 + row) * K + kb * 8;
        aofs[j] = s * 8;
    }
    const _Float16* gB[4];
    int bofs[4];
    #pragma unroll
    for (int j = 0; j < 4; j++) {
        const int s   = t + 256 * j;
        const int row = s >> 3;
        const int kb  = (s & 7) ^ (row & 7);
        gB[j] = Bt + (size_t)(col0 + row) * K + kb * 8;
        bofs[j] = s * 8;
    }

    #pragma unroll
    for (int j = 0; j < MI; j++) gl_lds16(gA[j], &As[0][aofs[j]]);
    #pragma unroll
    for (int j = 0; j < 4; j++)  gl_lds16(gB[j], &Bs[0][bofs[j]]);
    #pragma unroll
    for (int j = 0; j < MI; j++) gA[j] += 64;
    #pragma unroll
    for (int j = 0; j < 4; j++)  gB[j] += 64;

    const int niter = K >> 6;
    #pragma unroll 1
    for (int it = 0; it < niter; it++) {
        const int cur = it & 1;
        __syncthreads();

        if (it + 1 < niter) {
            const int nxt = cur ^ 1;
            #pragma unroll
            for (int j = 0; j < MI; j++) gl_lds16(gA[j], &As[nxt][aofs[j]]);
            #pragma unroll
            for (int j = 0; j < 4; j++)  gl_lds16(gB[j], &Bs[nxt][bofs[j]]);
            #pragma unroll
            for (int j = 0; j < MI; j++) gA[j] += 64;
            #pragma unroll
            for (int j = 0; j < 4; j++)  gB[j] += 64;
        }

        const _Float16* AsC = &As[cur][0];
        const _Float16* BsC = &Bs[cur][0];
        f16x8 af[MI][2], bf[4][2];
        #pragma unroll
        for (int i = 0; i < MI; i++) {
            const int arow = wr * (BM / 2) + i * 16 + l16;
            #pragma unroll
            for (int hh = 0; hh < 2; hh++)
                af[i][hh] = *(const f16x8*)(AsC + (arow * 8 + ((hh * 4 + quad) ^ sw)) * 8);
        }
        #pragma unroll
        for (int j = 0; j < 4; j++) {
            const int brow = wc * 64 + j * 16 + l16;
            #pragma unroll
            for (int hh = 0; hh < 2; hh++)
                bf[j][hh] = *(const f16x8*)(BsC + (brow * 8 + ((hh * 4 + quad) ^ sw)) * 8);
        }
        #pragma unroll
        for (int i = 0; i < MI; i++)
            #pragma unroll
            for (int j = 0; j < 4; j++) {
                acc[i][j] = __builtin_amdgcn_mfma_f32_16x16x32_f16(af[i][0], bf[j][0], acc[i][j], 0, 0, 0);
                acc[i][j] = __builtin_amdgcn_mfma_f32_16x16x32_f16(af[i][1], bf[j][1], acc[i][j], 0, 0, 0);
            }
    }

    #pragma unroll
    for (int j = 0; j < 4; j++) {
        const int col = col0 + wc * 64 + j * 16 + l16;
        const float bv = bias[col];
        #pragma unroll
        for (int i = 0; i < MI; i++) {
            const int row = row0 + wr * (BM / 2) + i * 16 + quad * 4;
            #pragma unroll
            for (int r = 0; r < 4; r++)
                Cout[(size_t)(row + r) * N + col] = acc[i][j][r] + bv;
        }
    }
}

// ---------------------------------------------------------------------------
// MFMA flash attention — in-register P (32x32x16), ONE __syncthreads per
// tile, XCD-clustered swizzle, 1-mul exp, setprio (all R9-proven).
// R10: lrow via 8x v_dot2_f32_f16 on the packed P words against (1,1)
// (replaces 16 f32 adds; denominator = rounded-P sum, R4 precedent).
// ---------------------------------------------------------------------------
__global__ __launch_bounds__(256, 4)
void flash_attn_kernel(const _Float16* __restrict__ qkv,
                       const _Float16* __restrict__ vtg,
                       _Float16* __restrict__ out)
{
    const int lin = blockIdx.y * 32 + blockIdx.x;   // 0..1023
    const int bh  = (lin & 7) * 4 + (lin >> 8);     // 0..31
    const int qt  = (lin >> 3) & 31;                // 0..31
    const int b  = bh >> 4, hd = bh & 15;
    const int t    = threadIdx.x;
    const int w    = t >> 6;
    const int lane = t & 63;
    const int qg   = w >> 1;            // q-group (32 rows)
    const int kh   = w & 1;             // key-half (32 keys)
    const int l31  = lane & 31;
    const int hf   = lane >> 5;         // lane half
    const int l7   = lane & 7;

    __shared__ __align__(16) _Float16 Ks [2][64 * 64];
    __shared__ __align__(16) _Float16 Vts[2][64 * 64];

    const int q0 = qt * 64;
    const size_t rstr = 3 * DIMM;
    const _Float16* qbase = qkv + (size_t)b * SEQ * rstr;

    f16x8 qf[4];
    {
        const _Float16* qrow = qbase + (size_t)(q0 + qg * 32 + l31) * rstr + hd * HDIM;
        #pragma unroll
        for (int dd = 0; dd < 4; dd++)
            qf[dd] = *(const f16x8*)(qrow + dd * 16 + hf * 8);
    }

    f32x16 Oacc[2];
    #pragma unroll
    for (int dh = 0; dh < 2; dh++)
        #pragma unroll
        for (int r = 0; r < 16; r++) Oacc[dh][r] = 0.f;
    float lrow = 0.f;
    const h2 k1 = {(_Float16)1.f, (_Float16)1.f};

    const int seg0 = t, seg1 = t + 256;
    const int r0 = seg0 >> 3, lb0 = (seg0 & 7) ^ (r0 & 7);
    const int r1 = seg1 >> 3, lb1 = (seg1 & 7) ^ (r1 & 7);
    const _Float16* gK0 = qbase + (size_t)r0 * rstr + DIMM + hd * HDIM + lb0 * 8;
    const _Float16* gK1 = qbase + (size_t)r1 * rstr + DIMM + hd * HDIM + lb1 * 8;
    const _Float16* gV0 = vtg + ((size_t)bh * 64 + r0) * SEQ + lb0 * 8;
    const _Float16* gV1 = vtg + ((size_t)bh * 64 + r1) * SEQ + lb1 * 8;

    gl_lds16(gK0, &Ks [0][seg0 * 8]);
    gl_lds16(gK1, &Ks [0][seg1 * 8]);
    gl_lds16(gV0, &Vts[0][seg0 * 8]);
    gl_lds16(gV1, &Vts[0][seg1 * 8]);

    #pragma unroll 2
    for (int k0 = 0; k0 < SEQ; k0 += 64) {
        const int cur = (k0 >> 6) & 1;
        const _Float16* KsC  = &Ks [cur][0];
        const _Float16* VtsC = &Vts[cur][0];

        __syncthreads();

        f32x16 sacc;
        #pragma unroll
        for (int r = 0; r < 16; r++) sacc[r] = 0.f;
        __builtin_amdgcn_s_setprio(1);
        #pragma unroll
        for (int dd = 0; dd < 4; dd++) {
            f16x8 kf = *(const f16x8*)(KsC + (kh * 32 + l31) * 64 + (((dd * 2 + hf) ^ l7) * 8));
            sacc = __builtin_amdgcn_mfma_f32_32x32x16_f16(kf, qf[dd], sacc, 0, 0, 0);
        }
        __builtin_amdgcn_s_setprio(0);

        if (k0 + 64 < SEQ) {
            const int nxt = cur ^ 1;
            gl_lds16(gK0 + (size_t)(k0 + 64) * rstr, &Ks [nxt][seg0 * 8]);
            gl_lds16(gK1 + (size_t)(k0 + 64) * rstr, &Ks [nxt][seg1 * 8]);
            gl_lds16(gV0 + (k0 + 64),                &Vts[nxt][seg0 * 8]);
            gl_lds16(gV1 + (k0 + 64),                &Vts[nxt][seg1 * 8]);
        }

        // e = 2^(s * 0.125*log2e) — one mul + v_exp_f32 per element
        float e[16];
        #pragma unroll
        for (int r = 0; r < 16; r++) {
            const float xx = sacc[r] * 0.18033688011112042f;   // 0.125*log2(e)
            float ee;
            asm("v_exp_f32 %0, %1" : "=v"(ee) : "v"(xx));
            e[r] = ee;
        }

        unsigned w01 = __builtin_bit_cast(unsigned, __builtin_amdgcn_cvt_pkrtz(e[0],  e[1]));
        unsigned w23 = __builtin_bit_cast(unsigned, __builtin_amdgcn_cvt_pkrtz(e[2],  e[3]));
        unsigned w45 = __builtin_bit_cast(unsigned, __builtin_amdgcn_cvt_pkrtz(e[4],  e[5]));
        unsigned w67 = __builtin_bit_cast(unsigned, __builtin_amdgcn_cvt_pkrtz(e[6],  e[7]));
        unsigned w89 = __builtin_bit_cast(unsigned, __builtin_amdgcn_cvt_pkrtz(e[8],  e[9]));
        unsigned wab = __builtin_bit_cast(unsigned, __builtin_amdgcn_cvt_pkrtz(e[10], e[11]));
        unsigned wcd = __builtin_bit_cast(unsigned, __builtin_amdgcn_cvt_pkrtz(e[12], e[13]));
        unsigned wef = __builtin_bit_cast(unsigned, __builtin_amdgcn_cvt_pkrtz(e[14], e[15]));

        // lrow += sum of packed P (rounded-P denominator; 8 v_dot2_f32_f16)
        lrow = __builtin_amdgcn_fdot2(__builtin_bit_cast(h2, w01), k1, lrow, false);
        lrow = __builtin_amdgcn_fdot2(__builtin_bit_cast(h2, w23), k1, lrow, false);
        lrow = __builtin_amdgcn_fdot2(__builtin_bit_cast(h2, w45), k1, lrow, false);
        lrow = __builtin_amdgcn_fdot2(__builtin_bit_cast(h2, w67), k1, lrow, false);
        lrow = __builtin_amdgcn_fdot2(__builtin_bit_cast(h2, w89), k1, lrow, false);
        lrow = __builtin_amdgcn_fdot2(__builtin_bit_cast(h2, wab), k1, lrow, false);
        lrow = __builtin_amdgcn_fdot2(__builtin_bit_cast(h2, wcd), k1, lrow, false);
        lrow = __builtin_amdgcn_fdot2(__builtin_bit_cast(h2, wef), k1, lrow, false);

        unsigned p00 = w01, p02 = w45;
        asm("v_permlane32_swap_b32 %0, %1" : "+v"(p00), "+v"(p02));
        unsigned p01 = w23, p03 = w67;
        asm("v_permlane32_swap_b32 %0, %1" : "+v"(p01), "+v"(p03));
        unsigned p10 = w89, p12 = wcd;
        asm("v_permlane32_swap_b32 %0, %1" : "+v"(p10), "+v"(p12));
        unsigned p11 = wab, p13 = wef;
        asm("v_permlane32_swap_b32 %0, %1" : "+v"(p11), "+v"(p13));
        f16x8 pa0 = mkfrag(p00, p01, p02, p03);
        f16x8 pa1 = mkfrag(p10, p11, p12, p13);

        __builtin_amdgcn_s_setprio(1);
        #pragma unroll
        for (int dh = 0; dh < 2; dh++) {
            const _Float16* vrow = VtsC + (dh * 32 + l31) * 64;
            f16x8 vf0 = *(const f16x8*)(vrow + (((kh * 4 + 0 + hf) ^ l7) * 8));
            f16x8 vf1 = *(const f16x8*)(vrow + (((kh * 4 + 2 + hf) ^ l7) * 8));
            Oacc[dh] = __builtin_amdgcn_mfma_f32_32x32x16_f16(pa0, vf0, Oacc[dh], 0, 0, 0);
            Oacc[dh] = __builtin_amdgcn_mfma_f32_32x32x16_f16(pa1, vf1, Oacc[dh], 0, 0, 0);
        }
        __builtin_amdgcn_s_setprio(0);
    }

    float lsum = lrow + __shfl_xor(lrow, 32);
    __syncthreads();
    float* Obuf = (float*)&Ks[0][0];
    float* lbuf = (float*)&Vts[0][0];
    if (kh) {
        #pragma unroll
        for (int dh = 0; dh < 2; dh++)
            #pragma unroll
            for (int r = 0; r < 16; r++) {
                const int q = (r & 3) + 8 * (r >> 2) + 4 * hf;
                Obuf[(qg * 32 + q) * 64 + dh * 32 + l31] = Oacc[dh][r];
            }
        if (lane < 32) lbuf[qg * 32 + lane] = lsum;
    }
    __syncthreads();
    if (!kh) {
        const float dnrec = 1.f / (lsum + lbuf[qg * 32 + l31]);
        float dq[16];
        #pragma unroll
        for (int r = 0; r < 16; r++)
            dq[r] = __shfl(dnrec, (r & 3) + 8 * (r >> 2) + 4 * hf);
        #pragma unroll
        for (int dh = 0; dh < 2; dh++)
            #pragma unroll
            for (int r = 0; r < 16; r++) {
                const int q = (r & 3) + 8 * (r >> 2) + 4 * hf;
                const float v = (Oacc[dh][r] + Obuf[(qg * 32 + q) * 64 + dh * 32 + l31])
                                * dq[r];
                out[(size_t)(b * SEQ + q0 + qg * 32 + q) * DIMM + hd * HDIM + dh * 32 + l31] =
                    (_Float16)v;
            }
    }
}

// ---------------------------------------------------------------------------
extern "C" void kernel_launch(void* const* d_in, const int* in_sizes, int n_in,
                              void* d_out, int out_size, void* d_ws, size_t ws_size,
                              hipStream_t stream)
{
    const float* x    = (const float*)d_in[0];   // [2,2048,1024]
    const float* Wqkv = (const float*)d_in[1];   // [1024,3072]
    const float* bqkv = (const float*)d_in[2];   // [3072]
    const float* Wout = (const float*)d_in[3];   // [1024,1024]
    const float* bout = (const float*)d_in[4];   // [1024]
    float* out = (float*)d_out;                  // [2,2048,1024]

    _Float16* qkvh  = (_Float16*)d_ws;                   // 4096x3072 (V-third unused)
    _Float16* attnh = qkvh  + (size_t)ROWS * 3 * DIMM;   // 4096x1024
    _Float16* xh    = attnh + (size_t)ROWS * DIMM;       // 4096x1024 (unused now)
    _Float16* wqkvt = xh    + (size_t)ROWS * DIMM;       // 3072x1024
    _Float16* woutt = wqkvt + (size_t)3 * DIMM * DIMM;   // 1024x1024
    _Float16* vtg   = woutt + (size_t)DIMM * DIMM;       // 32 x 64 x 2048

    // 0) weight transposes only (x conversion fused into qkv GEMM)
    prep_kernel<<<1024, 256, 0, stream>>>(Wqkv, Wout, wqkvt, woutt);
    // 1) qkv = x @ W_qkv + b_qkv (A = x f32, fused cvt); V-third -> vtg transposed
    {
        dim3 grid(3 * DIMM / 256, ROWS / 256);   // (12,16)
        hgemm256_kernel<<<grid, 512, 0, stream>>>(x, wqkvt, bqkv, qkvh, vtg, 3 * DIMM, DIMM);
    }
    // 2) attention -> attnh (fp16)
    {
        dim3 grid(SEQ / 64, BATCH * NHEADS);
        flash_attn_kernel<<<grid, 256, 0, stream>>>(qkvh, vtg, attnh);
    }
    // 3) out = attn @ W_out + b_out (fp32) — 64x128 dbuf, 512 blocks
    {
        dim3 grid(DIMM / 128, ROWS / 64);
        hgemm_out_kernel<<<grid, 256, 0, stream>>>(attnh, woutt, bout, out, DIMM, DIMM);
    }
}

// Round 11
// 186.719 us; speedup vs baseline: 1.0082x; 1.0023x over previous
//
#include <hip/hip_runtime.h>
#include <math.h>

// Problem constants (AttentionLikeModel_75531294867774)
#define DIMM    1024
#define NHEADS  16
#define HDIM    64
#define BATCH   2
#define SEQ     2048
#define ROWS    (BATCH*SEQ)   // 4096

typedef _Float16 f16x8 __attribute__((ext_vector_type(8)));
typedef _Float16 f16x4 __attribute__((ext_vector_type(4)));
typedef _Float16 h2    __attribute__((ext_vector_type(2)));
typedef float    f32x4 __attribute__((ext_vector_type(4)));
typedef float    f32x16 __attribute__((ext_vector_type(16)));

__device__ inline void gl_lds16(const void* g, void* l) {
    __builtin_amdgcn_global_load_lds(
        (const __attribute__((address_space(1))) void*)g,
        (__attribute__((address_space(3))) void*)l, 16, 0, 0);
}

static __device__ inline f16x8 mkfrag(unsigned a, unsigned b, unsigned c, unsigned d) {
    union { unsigned u[4]; f16x8 v; } x;
    x.u[0] = a; x.u[1] = b; x.u[2] = c; x.u[3] = d;
    return x.v;
}
static __device__ inline f16x8 cvt8(const float4& a, const float4& b) {
    unsigned u0 = __builtin_bit_cast(unsigned, __builtin_amdgcn_cvt_pkrtz(a.x, a.y));
    unsigned u1 = __builtin_bit_cast(unsigned, __builtin_amdgcn_cvt_pkrtz(a.z, a.w));
    unsigned u2 = __builtin_bit_cast(unsigned, __builtin_amdgcn_cvt_pkrtz(b.x, b.y));
    unsigned u3 = __builtin_bit_cast(unsigned, __builtin_amdgcn_cvt_pkrtz(b.z, b.w));
    return mkfrag(u0, u1, u2, u3);
}

// ---------------------------------------------------------------------------
// Prep (weights only): blocks [0,768) W_qkv^T; [768,1024) W_out^T.
// ---------------------------------------------------------------------------
__device__ void tcvt64(const float* __restrict__ in, _Float16* __restrict__ out,
                       int K, int N, int k0, int n0, float (*tile)[65], int t)
{
    {
        const int c4 = (t & 15) * 4;
        const int r  = t >> 4;
        #pragma unroll
        for (int i = 0; i < 4; i++) {
            const int rr = r + 16 * i;
            float4 v = *(const float4*)(in + (size_t)(k0 + rr) * N + n0 + c4);
            tile[rr][c4] = v.x; tile[rr][c4 + 1] = v.y;
            tile[rr][c4 + 2] = v.z; tile[rr][c4 + 3] = v.w;
        }
    }
    __syncthreads();
    #pragma unroll
    for (int i = 0; i < 2; i++) {
        const int seg = t + 256 * i;
        const int n   = seg >> 3;
        const int kc  = (seg & 7) * 8;
        f16x8 o;
        #pragma unroll
        for (int j = 0; j < 8; j++) o[j] = (_Float16)tile[kc + j][n];
        *(f16x8*)(out + (size_t)(n0 + n) * K + k0 + kc) = o;
    }
}

__global__ __launch_bounds__(256)
void prep_kernel(const float* __restrict__ Wqkv, const float* __restrict__ Wout,
                 _Float16* __restrict__ wqkvt, _Float16* __restrict__ woutt)
{
    __shared__ float tile[64][65];
    const int bx = blockIdx.x;
    const int t  = threadIdx.x;
    if (bx < 768) {                        // W_qkv^T: grid (48,16)
        const int gx = bx % 48, gy = bx / 48;
        tcvt64(Wqkv, wqkvt, DIMM, 3 * DIMM, gy * 64, gx * 64, tile, t);
    } else {                               // W_out^T: grid (16,16)
        const int id = bx - 768;
        const int gx = id & 15, gy = id >> 4;
        tcvt64(Wout, woutt, DIMM, DIMM, gy * 64, gx * 64, tile, t);
    }
}

// ---------------------------------------------------------------------------
// qkv HGEMM 256x192, 8 waves (512 thr), 32x32x16 MFMA, A = x f32 (fused cvt).
// R11: tile 256x192 -> grid (16,16) = 256 blocks = EXACTLY 1 block/CU (100%
// CU coverage; the 256x256 version had 192 blocks -> 64 CUs idle).
// Wave grid 4m x 2n: per-wave 64x96 = 2x3 32x32 tiles, acc[2][3].
// LDS 112 KB: A bufs 2x32K @ 0/16384, B bufs 2x24K @ 32768/+12288.
// Sync = R4-proven one-__syncthreads-per-iter dbuf (writes->buf[nxt],
// reads->buf[cur]). Q|K|V col-2048 boundary is NOT tile-aligned: all blocks
// run a col<2048-predicated direct store (wave-uniform per 32-col group);
// blocks bx>=10 additionally stage cols>=2048 via LDS -> vtg 128B runs.
// Coverage audit: stage sidx=rq+4mi+8wm spans 0..31 segs, cols 0..191;
// read-out cs=half*16+c (c<16) spans 0..31; bx=10 stages coll in [128,192).
// ---------------------------------------------------------------------------
__global__ __launch_bounds__(512)
void hgemm256_kernel(const float* __restrict__ X, const _Float16* __restrict__ Bt,
                     const float* __restrict__ bias, _Float16* __restrict__ C,
                     _Float16* __restrict__ vtg, int N, int K)
{
    __shared__ __align__(16) _Float16 lds[57344];   // 112 KB

    const int t    = threadIdx.x;
    const int w    = t >> 6, lane = t & 63;
    const int l31  = lane & 31;
    const int hf   = lane >> 5;
    const int l7   = lane & 7;
    const int wm   = w >> 1;            // 0..3 -> m-offset wm*64
    const int wn   = w & 1;             // 0..1 -> n-offset wn*96
    const int row0 = blockIdx.y * 256, col0 = blockIdx.x * 192;

    f32x16 acc[2][3];
    #pragma unroll
    for (int mi = 0; mi < 2; mi++)
        #pragma unroll
        for (int ni = 0; ni < 3; ni++)
            #pragma unroll
            for (int r = 0; r < 16; r++) acc[mi][ni][r] = 0.f;

    // staging: A 4 16B-segs/thread (2048 segs), B 3 segs/thread (1536 segs)
    const float*    gAf[4];
    int aofs[4];
    #pragma unroll
    for (int j = 0; j < 4; j++) {
        const int s   = t + 512 * j;
        const int row = s >> 3;
        const int kb  = (s & 7) ^ (row & 7);
        gAf[j] = X + (size_t)(row0 + row) * K + kb * 8;
        aofs[j] = s * 8;
    }
    const _Float16* gB[3];
    int bofs[3];
    #pragma unroll
    for (int j = 0; j < 3; j++) {
        const int s   = t + 512 * j;
        const int row = s >> 3;
        const int kb  = (s & 7) ^ (row & 7);
        gB[j] = Bt + (size_t)(col0 + row) * K + kb * 8;
        bofs[j] = s * 8;
    }

    // prologue: stage tile 0 into buffer 0 (A via regs+cvt, B via DMA)
    {
        float4 pa[4], pb[4];
        #pragma unroll
        for (int j = 0; j < 4; j++) {
            pa[j] = *(const float4*)(gAf[j]);
            pb[j] = *(const float4*)(gAf[j] + 4);
        }
        #pragma unroll
        for (int j = 0; j < 4; j++) *(f16x8*)(lds + aofs[j]) = cvt8(pa[j], pb[j]);
        #pragma unroll
        for (int j = 0; j < 3; j++) gl_lds16(gB[j], lds + 32768 + bofs[j]);
        #pragma unroll
        for (int j = 0; j < 4; j++) gAf[j] += 64;
        #pragma unroll
        for (int j = 0; j < 3; j++) gB[j] += 64;
    }

    const int niter = K >> 6;   // 16
    #pragma unroll 1
    for (int it = 0; it < niter; it++) {
        const int cur = it & 1;
        __syncthreads();        // drains buf[cur] A-writes + B-DMAs; joins buf[cur^1] reads

        float4 pa[4], pb[4];
        const int nxt = cur ^ 1;
        if (it + 1 < niter) {
            #pragma unroll
            for (int j = 0; j < 4; j++) {
                pa[j] = *(const float4*)(gAf[j]);
                pb[j] = *(const float4*)(gAf[j] + 4);
            }
            #pragma unroll
            for (int j = 0; j < 3; j++)
                gl_lds16(gB[j], lds + 32768 + nxt * 12288 + bofs[j]);
            #pragma unroll
            for (int j = 0; j < 4; j++) gAf[j] += 64;
            #pragma unroll
            for (int j = 0; j < 3; j++) gB[j] += 64;
        }

        const _Float16* AsC = lds + cur * 16384;
        const _Float16* BsC = lds + 32768 + cur * 12288;
        #pragma unroll
        for (int ks = 0; ks < 4; ks++) {
            const int pseg = ((ks * 2 + hf) ^ l7) * 8;
            f16x8 bf[3];
            #pragma unroll
            for (int ni = 0; ni < 3; ni++)
                bf[ni] = *(const f16x8*)(BsC + (wn * 96 + ni * 32 + l31) * 64 + pseg);
            #pragma unroll
            for (int mi = 0; mi < 2; mi++) {
                f16x8 af = *(const f16x8*)(AsC + (wm * 64 + mi * 32 + l31) * 64 + pseg);
                #pragma unroll
                for (int ni = 0; ni < 3; ni++)
                    acc[mi][ni] = __builtin_amdgcn_mfma_f32_32x32x16_f16(af, bf[ni], acc[mi][ni], 0, 0, 0);
            }
        }

        if (it + 1 < niter) {
            #pragma unroll
            for (int j = 0; j < 4; j++)
                *(f16x8*)(lds + nxt * 16384 + aofs[j]) = cvt8(pa[j], pb[j]);
        }
    }

    float bv[3];
    #pragma unroll
    for (int ni = 0; ni < 3; ni++) bv[ni] = bias[col0 + wn * 96 + ni * 32 + l31];

    // direct Q/K store (cols < 2048); predicate is uniform per (wn,ni) group
    #pragma unroll
    for (int mi = 0; mi < 2; mi++)
        #pragma unroll
        for (int ni = 0; ni < 3; ni++) {
            const int col = col0 + wn * 96 + ni * 32 + l31;
            if (col < 2048) {
                #pragma unroll
                for (int r = 0; r < 16; r++) {
                    const int row = row0 + wm * 64 + mi * 32 + (r & 3) + 8 * (r >> 2) + 4 * hf;
                    C[(size_t)row * N + col] = (_Float16)(acc[mi][ni][r] + bv[ni]);
                }
            }
        }

    if (col0 + 192 <= 2048) return;     // pure Q/K block (bx <= 9)

    // V cols (>= 2048): transpose via LDS -> vtg[bh][d][key], 128B runs.
    __syncthreads();                    // all buf reads done; lds reusable
    #pragma unroll
    for (int mi = 0; mi < 2; mi++)
        #pragma unroll
        for (int ni = 0; ni < 3; ni++) {
            const int coll = wn * 96 + ni * 32 + l31;
            if (col0 + coll >= 2048) {
                #pragma unroll
                for (int rq = 0; rq < 4; rq++) {
                    f16x4 o;
                    #pragma unroll
                    for (int ri = 0; ri < 4; ri++) o[ri] = (_Float16)(acc[mi][ni][rq * 4 + ri] + bv[ni]);
                    const int sidx = rq + 4 * mi + 8 * wm;       // 16B seg along key, 0..31
                    *(f16x4*)(lds + coll * 256 + ((sidx ^ (coll & 31)) << 3) + 4 * hf) = o;
                }
            }
        }
    __syncthreads();
    {
        const int cl   = t >> 1;            // col_local 0..255 (use < 192)
        const int half = t & 1;             // key half 0/1
        if (cl < 192) {
            const int col = col0 + cl;
            if (col >= 2048) {
                const int head = (col - 2048) >> 6;
                const int dv   = (col - 2048) & 63;
                const int bb   = blockIdx.y >> 3;   // batch
                const int key0 = (blockIdx.y & 7) * 256 + half * 128;
                _Float16* dst = vtg + ((size_t)(bb * 16 + head) * 64 + dv) * SEQ + key0;
                #pragma unroll
                for (int c = 0; c < 16; c++) {
                    const int cs = half * 16 + c;   // 16B seg along key, 0..31
                    *(f16x8*)(dst + c * 8) = *(const f16x8*)(lds + cl * 256 + ((cs ^ (cl & 31)) << 3));
                }
            }
        }
    }
}

// ---------------------------------------------------------------------------
// out-GEMM: 64x128 dbuf pipelined, one __syncthreads per iter. UNCHANGED.
// ---------------------------------------------------------------------------
__global__ __launch_bounds__(256)
void hgemm_out_kernel(const _Float16* __restrict__ A, const _Float16* __restrict__ Bt,
                      const float* __restrict__ bias, float* __restrict__ Cout,
                      int N, int K)
{
    constexpr int BM = 64, MI = 2;
    __shared__ _Float16 As[2][BM * 64];
    __shared__ _Float16 Bs[2][128 * 64];

    const int t    = threadIdx.x;
    const int w    = t >> 6, lane = t & 63;
    const int quad = lane >> 4, l16 = lane & 15;
    const int wr   = w >> 1, wc = w & 1;
    const int row0 = blockIdx.y * BM, col0 = blockIdx.x * 128;
    const int sw   = l16 & 7;

    f32x4 acc[MI][4];
    #pragma unroll
    for (int i = 0; i < MI; i++)
        #pragma unroll
        for (int j = 0; j < 4; j++)
            #pragma unroll
            for (int r = 0; r < 4; r++) acc[i][j][r] = 0.f;

    const _Float16* gA[MI];
    int aofs[MI];
    #pragma unroll
    for (int j = 0; j < MI; j++) {
        const int s   = t + 256 * j;
        const int row = s >> 3;
        const int kb  = (s & 7) ^ (row & 7);
        gA[j] = A + (size_t)(row0 + row) * K + kb * 8;
        aofs[j] = s * 8;
    }
    const _Float16* gB[4];
    int bofs[4];
    #pragma unroll
    for (int j = 0; j < 4; j++) {
        const int s   = t + 256 * j;
        const int row = s >> 3;
        const int kb  = (s & 7) ^ (row & 7);
        gB[j] = Bt + (size_t)(col0 + row) * K + kb * 8;
        bofs[j] = s * 8;
    }

    #pragma unroll
    for (int j = 0; j < MI; j++) gl_lds16(gA[j], &As[0][aofs[j]]);
    #pragma unroll
    for (int j = 0; j < 4; j++)  gl_lds16(gB[j], &Bs[0][bofs[j]]);
    #pragma unroll
    for (int j = 0; j < MI; j++) gA[j] += 64;
    #pragma unroll
    for (int j = 0; j < 4; j++)  gB[j] += 64;

    const int niter = K >> 6;
    #pragma unroll 1
    for (int it = 0; it < niter; it++) {
        const int cur = it & 1;
        __syncthreads();

        if (it + 1 < niter) {
            const int nxt = cur ^ 1;
            #pragma unroll
            for (int j = 0; j < MI; j++) gl_lds16(gA[j], &As[nxt][aofs[j]]);
            #pragma unroll
            for (int j = 0; j < 4; j++)  gl_lds16(gB[j], &Bs[nxt][bofs[j]]);
            #pragma unroll
            for (int j = 0; j < MI; j++) gA[j] += 64;
            #pragma unroll
            for (int j = 0; j < 4; j++)  gB[j] += 64;
        }

        const _Float16* AsC = &As[cur][0];
        const _Float16* BsC = &Bs[cur][0];
        f16x8 af[MI][2], bf[4][2];
        #pragma unroll
        for (int i = 0; i < MI; i++) {
            const int arow = wr * (BM / 2) + i * 16 + l16;
            #pragma unroll
            for (int hh = 0; hh < 2; hh++)
                af[i][hh] = *(const f16x8*)(AsC + (arow * 8 + ((hh * 4 + quad) ^ sw)) * 8);
        }
        #pragma unroll
        for (int j = 0; j < 4; j++) {
            const int brow = wc * 64 + j * 16 + l16;
            #pragma unroll
            for (int hh = 0; hh < 2; hh++)
                bf[j][hh] = *(const f16x8*)(BsC + (brow * 8 + ((hh * 4 + quad) ^ sw)) * 8);
        }
        #pragma unroll
        for (int i = 0; i < MI; i++)
            #pragma unroll
            for (int j = 0; j < 4; j++) {
                acc[i][j] = __builtin_amdgcn_mfma_f32_16x16x32_f16(af[i][0], bf[j][0], acc[i][j], 0, 0, 0);
                acc[i][j] = __builtin_amdgcn_mfma_f32_16x16x32_f16(af[i][1], bf[j][1], acc[i][j], 0, 0, 0);
            }
    }

    #pragma unroll
    for (int j = 0; j < 4; j++) {
        const int col = col0 + wc * 64 + j * 16 + l16;
        const float bv = bias[col];
        #pragma unroll
        for (int i = 0; i < MI; i++) {
            const int row = row0 + wr * (BM / 2) + i * 16 + quad * 4;
            #pragma unroll
            for (int r = 0; r < 4; r++)
                Cout[(size_t)(row + r) * N + col] = acc[i][j][r] + bv;
        }
    }
}

// ---------------------------------------------------------------------------
// MFMA flash attention — UNCHANGED from round 10 (52.1 µs, absmax 4.88e-4):
// in-register P (32x32x16), ONE __syncthreads per tile, XCD-clustered
// swizzle, 1-mul exp, setprio, fdot2 denominator.
// ---------------------------------------------------------------------------
__global__ __launch_bounds__(256, 4)
void flash_attn_kernel(const _Float16* __restrict__ qkv,
                       const _Float16* __restrict__ vtg,
                       _Float16* __restrict__ out)
{
    const int lin = blockIdx.y * 32 + blockIdx.x;   // 0..1023
    const int bh  = (lin & 7) * 4 + (lin >> 8);     // 0..31
    const int qt  = (lin >> 3) & 31;                // 0..31
    const int b  = bh >> 4, hd = bh & 15;
    const int t    = threadIdx.x;
    const int w    = t >> 6;
    const int lane = t & 63;
    const int qg   = w >> 1;            // q-group (32 rows)
    const int kh   = w & 1;             // key-half (32 keys)
    const int l31  = lane & 31;
    const int hf   = lane >> 5;         // lane half
    const int l7   = lane & 7;

    __shared__ __align__(16) _Float16 Ks [2][64 * 64];
    __shared__ __align__(16) _Float16 Vts[2][64 * 64];

    const int q0 = qt * 64;
    const size_t rstr = 3 * DIMM;
    const _Float16* qbase = qkv + (size_t)b * SEQ * rstr;

    f16x8 qf[4];
    {
        const _Float16* qrow = qbase + (size_t)(q0 + qg * 32 + l31) * rstr + hd * HDIM;
        #pragma unroll
        for (int dd = 0; dd < 4; dd++)
            qf[dd] = *(const f16x8*)(qrow + dd * 16 + hf * 8);
    }

    f32x16 Oacc[2];
    #pragma unroll
    for (int dh = 0; dh < 2; dh++)
        #pragma unroll
        for (int r = 0; r < 16; r++) Oacc[dh][r] = 0.f;
    float lrow = 0.f;
    const h2 k1 = {(_Float16)1.f, (_Float16)1.f};

    const int seg0 = t, seg1 = t + 256;
    const int r0 = seg0 >> 3, lb0 = (seg0 & 7) ^ (r0 & 7);
    const int r1 = seg1 >> 3, lb1 = (seg1 & 7) ^ (r1 & 7);
    const _Float16* gK0 = qbase + (size_t)r0 * rstr + DIMM + hd * HDIM + lb0 * 8;
    const _Float16* gK1 = qbase + (size_t)r1 * rstr + DIMM + hd * HDIM + lb1 * 8;
    const _Float16* gV0 = vtg + ((size_t)bh * 64 + r0) * SEQ + lb0 * 8;
    const _Float16* gV1 = vtg + ((size_t)bh * 64 + r1) * SEQ + lb1 * 8;

    gl_lds16(gK0, &Ks [0][seg0 * 8]);
    gl_lds16(gK1, &Ks [0][seg1 * 8]);
    gl_lds16(gV0, &Vts[0][seg0 * 8]);
    gl_lds16(gV1, &Vts[0][seg1 * 8]);

    #pragma unroll 2
    for (int k0 = 0; k0 < SEQ; k0 += 64) {
        const int cur = (k0 >> 6) & 1;
        const _Float16* KsC  = &Ks [cur][0];
        const _Float16* VtsC = &Vts[cur][0];

        __syncthreads();

        f32x16 sacc;
        #pragma unroll
        for (int r = 0; r < 16; r++) sacc[r] = 0.f;
        __builtin_amdgcn_s_setprio(1);
        #pragma unroll
        for (int dd = 0; dd < 4; dd++) {
            f16x8 kf = *(const f16x8*)(KsC + (kh * 32 + l31) * 64 + (((dd * 2 + hf) ^ l7) * 8));
            sacc = __builtin_amdgcn_mfma_f32_32x32x16_f16(kf, qf[dd], sacc, 0, 0, 0);
        }
        __builtin_amdgcn_s_setprio(0);

        if (k0 + 64 < SEQ) {
            const int nxt = cur ^ 1;
            gl_lds16(gK0 + (size_t)(k0 + 64) * rstr, &Ks [nxt][seg0 * 8]);
            gl_lds16(gK1 + (size_t)(k0 + 64) * rstr, &Ks [nxt][seg1 * 8]);
            gl_lds16(gV0 + (k0 + 64),                &Vts[nxt][seg0 * 8]);
            gl_lds16(gV1 + (k0 + 64),                &Vts[nxt][seg1 * 8]);
        }

        float e[16];
        #pragma unroll
        for (int r = 0; r < 16; r++) {
            const float xx = sacc[r] * 0.18033688011112042f;   // 0.125*log2(e)
            float ee;
            asm("v_exp_f32 %0, %1" : "=v"(ee) : "v"(xx));
            e[r] = ee;
        }

        unsigned w01 = __builtin_bit_cast(unsigned, __builtin_amdgcn_cvt_pkrtz(e[0],  e[1]));
        unsigned w23 = __builtin_bit_cast(unsigned, __builtin_amdgcn_cvt_pkrtz(e[2],  e[3]));
        unsigned w45 = __builtin_bit_cast(unsigned, __builtin_amdgcn_cvt_pkrtz(e[4],  e[5]));
        unsigned w67 = __builtin_bit_cast(unsigned, __builtin_amdgcn_cvt_pkrtz(e[6],  e[7]));
        unsigned w89 = __builtin_bit_cast(unsigned, __builtin_amdgcn_cvt_pkrtz(e[8],  e[9]));
        unsigned wab = __builtin_bit_cast(unsigned, __builtin_amdgcn_cvt_pkrtz(e[10], e[11]));
        unsigned wcd = __builtin_bit_cast(unsigned, __builtin_amdgcn_cvt_pkrtz(e[12], e[13]));
        unsigned wef = __builtin_bit_cast(unsigned, __builtin_amdgcn_cvt_pkrtz(e[14], e[15]));

        lrow = __builtin_amdgcn_fdot2(__builtin_bit_cast(h2, w01), k1, lrow, false);
        lrow = __builtin_amdgcn_fdot2(__builtin_bit_cast(h2, w23), k1, lrow, false);
        lrow = __builtin_amdgcn_fdot2(__builtin_bit_cast(h2, w45), k1, lrow, false);
        lrow = __builtin_amdgcn_fdot2(__builtin_bit_cast(h2, w67), k1, lrow, false);
        lrow = __builtin_amdgcn_fdot2(__builtin_bit_cast(h2, w89), k1, lrow, false);
        lrow = __builtin_amdgcn_fdot2(__builtin_bit_cast(h2, wab), k1, lrow, false);
        lrow = __builtin_amdgcn_fdot2(__builtin_bit_cast(h2, wcd), k1, lrow, false);
        lrow = __builtin_amdgcn_fdot2(__builtin_bit_cast(h2, wef), k1, lrow, false);

        unsigned p00 = w01, p02 = w45;
        asm("v_permlane32_swap_b32 %0, %1" : "+v"(p00), "+v"(p02));
        unsigned p01 = w23, p03 = w67;
        asm("v_permlane32_swap_b32 %0, %1" : "+v"(p01), "+v"(p03));
        unsigned p10 = w89, p12 = wcd;
        asm("v_permlane32_swap_b32 %0, %1" : "+v"(p10), "+v"(p12));
        unsigned p11 = wab, p13 = wef;
        asm("v_permlane32_swap_b32 %0, %1" : "+v"(p11), "+v"(p13));
        f16x8 pa0 = mkfrag(p00, p01, p02, p03);
        f16x8 pa1 = mkfrag(p10, p11, p12, p13);

        __builtin_amdgcn_s_setprio(1);
        #pragma unroll
        for (int dh = 0; dh < 2; dh++) {
            const _Float16* vrow = VtsC + (dh * 32 + l31) * 64;
            f16x8 vf0 = *(const f16x8*)(vrow + (((kh * 4 + 0 + hf) ^ l7) * 8));
            f16x8 vf1 = *(const f16x8*)(vrow + (((kh * 4 + 2 + hf) ^ l7) * 8));
            Oacc[dh] = __builtin_amdgcn_mfma_f32_32x32x16_f16(pa0, vf0, Oacc[dh], 0, 0, 0);
            Oacc[dh] = __builtin_amdgcn_mfma_f32_32x32x16_f16(pa1, vf1, Oacc[dh], 0, 0, 0);
        }
        __builtin_amdgcn_s_setprio(0);
    }

    float lsum = lrow + __shfl_xor(lrow, 32);
    __syncthreads();
    float* Obuf = (float*)&Ks[0][0];
    float* lbuf = (float*)&Vts[0][0];
    if (kh) {
        #pragma unroll
        for (int dh = 0; dh < 2; dh++)
            #pragma unroll
            for (int r = 0; r < 16; r++) {
                const int q = (r & 3) + 8 * (r >> 2) + 4 * hf;
                Obuf[(qg * 32 + q) * 64 + dh * 32 + l31] = Oacc[dh][r];
            }
        if (lane < 32) lbuf[qg * 32 + lane] = lsum;
    }
    __syncthreads();
    if (!kh) {
        const float dnrec = 1.f / (lsum + lbuf[qg * 32 + l31]);
        float dq[16];
        #pragma unroll
        for (int r = 0; r < 16; r++)
            dq[r] = __shfl(dnrec, (r & 3) + 8 * (r >> 2) + 4 * hf);
        #pragma unroll
        for (int dh = 0; dh < 2; dh++)
            #pragma unroll
            for (int r = 0; r < 16; r++) {
                const int q = (r & 3) + 8 * (r >> 2) + 4 * hf;
                const float v = (Oacc[dh][r] + Obuf[(qg * 32 + q) * 64 + dh * 32 + l31])
                                * dq[r];
                out[(size_t)(b * SEQ + q0 + qg * 32 + q) * DIMM + hd * HDIM + dh * 32 + l31] =
                    (_Float16)v;
            }
    }
}

// ---------------------------------------------------------------------------
extern "C" void kernel_launch(void* const* d_in, const int* in_sizes, int n_in,
                              void* d_out, int out_size, void* d_ws, size_t ws_size,
                              hipStream_t stream)
{
    const float* x    = (const float*)d_in[0];   // [2,2048,1024]
    const float* Wqkv = (const float*)d_in[1];   // [1024,3072]
    const float* bqkv = (const float*)d_in[2];   // [3072]
    const float* Wout = (const float*)d_in[3];   // [1024,1024]
    const float* bout = (const float*)d_in[4];   // [1024]
    float* out = (float*)d_out;                  // [2,2048,1024]

    _Float16* qkvh  = (_Float16*)d_ws;                   // 4096x3072 (V-third unused)
    _Float16* attnh = qkvh  + (size_t)ROWS * 3 * DIMM;   // 4096x1024
    _Float16* xh    = attnh + (size_t)ROWS * DIMM;       // 4096x1024 (unused now)
    _Float16* wqkvt = xh    + (size_t)ROWS * DIMM;       // 3072x1024
    _Float16* woutt = wqkvt + (size_t)3 * DIMM * DIMM;   // 1024x1024
    _Float16* vtg   = woutt + (size_t)DIMM * DIMM;       // 32 x 64 x 2048

    // 0) weight transposes only
    prep_kernel<<<1024, 256, 0, stream>>>(Wqkv, Wout, wqkvt, woutt);
    // 1) qkv = x @ W_qkv + b_qkv (A = x f32, fused cvt); 256x192 tiles,
    //    grid (16,16) = 256 blocks = 1/CU; V cols -> vtg transposed
    {
        dim3 grid(3 * DIMM / 192, ROWS / 256);   // (16,16)
        hgemm256_kernel<<<grid, 512, 0, stream>>>(x, wqkvt, bqkv, qkvh, vtg, 3 * DIMM, DIMM);
    }
    // 2) attention -> attnh (fp16)
    {
        dim3 grid(SEQ / 64, BATCH * NHEADS);
        flash_attn_kernel<<<grid, 256, 0, stream>>>(qkvh, vtg, attnh);
    }
    // 3) out = attn @ W_out + b_out (fp32) — 64x128 dbuf, 512 blocks
    {
        dim3 grid(DIMM / 128, ROWS / 64);
        hgemm_out_kernel<<<grid, 256, 0, stream>>>(attnh, woutt, bout, out, DIMM, DIMM);
    }
}

// Round 12
// 186.548 us; speedup vs baseline: 1.0091x; 1.0009x over previous
//
#include <hip/hip_runtime.h>
#include <math.h>

// Problem constants (AttentionLikeModel_75531294867774)
#define DIMM    1024
#define NHEADS  16
#define HDIM    64
#define BATCH   2
#define SEQ     2048
#define ROWS    (BATCH*SEQ)   // 4096

typedef _Float16 f16x8 __attribute__((ext_vector_type(8)));
typedef _Float16 f16x4 __attribute__((ext_vector_type(4)));
typedef _Float16 h2    __attribute__((ext_vector_type(2)));
typedef float    f32x4 __attribute__((ext_vector_type(4)));
typedef float    f32x16 __attribute__((ext_vector_type(16)));

__device__ inline void gl_lds16(const void* g, void* l) {
    __builtin_amdgcn_global_load_lds(
        (const __attribute__((address_space(1))) void*)g,
        (__attribute__((address_space(3))) void*)l, 16, 0, 0);
}

static __device__ inline f16x8 mkfrag(unsigned a, unsigned b, unsigned c, unsigned d) {
    union { unsigned u[4]; f16x8 v; } x;
    x.u[0] = a; x.u[1] = b; x.u[2] = c; x.u[3] = d;
    return x.v;
}
static __device__ inline f16x8 cvt8(const float4& a, const float4& b) {
    unsigned u0 = __builtin_bit_cast(unsigned, __builtin_amdgcn_cvt_pkrtz(a.x, a.y));
    unsigned u1 = __builtin_bit_cast(unsigned, __builtin_amdgcn_cvt_pkrtz(a.z, a.w));
    unsigned u2 = __builtin_bit_cast(unsigned, __builtin_amdgcn_cvt_pkrtz(b.x, b.y));
    unsigned u3 = __builtin_bit_cast(unsigned, __builtin_amdgcn_cvt_pkrtz(b.z, b.w));
    return mkfrag(u0, u1, u2, u3);
}

// ---------------------------------------------------------------------------
// Prep (weights only): blocks [0,768) W_qkv^T; [768,1024) W_out^T. UNCHANGED.
// ---------------------------------------------------------------------------
__device__ void tcvt64(const float* __restrict__ in, _Float16* __restrict__ out,
                       int K, int N, int k0, int n0, float (*tile)[65], int t)
{
    {
        const int c4 = (t & 15) * 4;
        const int r  = t >> 4;
        #pragma unroll
        for (int i = 0; i < 4; i++) {
            const int rr = r + 16 * i;
            float4 v = *(const float4*)(in + (size_t)(k0 + rr) * N + n0 + c4);
            tile[rr][c4] = v.x; tile[rr][c4 + 1] = v.y;
            tile[rr][c4 + 2] = v.z; tile[rr][c4 + 3] = v.w;
        }
    }
    __syncthreads();
    #pragma unroll
    for (int i = 0; i < 2; i++) {
        const int seg = t + 256 * i;
        const int n   = seg >> 3;
        const int kc  = (seg & 7) * 8;
        f16x8 o;
        #pragma unroll
        for (int j = 0; j < 8; j++) o[j] = (_Float16)tile[kc + j][n];
        *(f16x8*)(out + (size_t)(n0 + n) * K + k0 + kc) = o;
    }
}

__global__ __launch_bounds__(256)
void prep_kernel(const float* __restrict__ Wqkv, const float* __restrict__ Wout,
                 _Float16* __restrict__ wqkvt, _Float16* __restrict__ woutt)
{
    __shared__ float tile[64][65];
    const int bx = blockIdx.x;
    const int t  = threadIdx.x;
    if (bx < 768) {                        // W_qkv^T: grid (48,16)
        const int gx = bx % 48, gy = bx / 48;
        tcvt64(Wqkv, wqkvt, DIMM, 3 * DIMM, gy * 64, gx * 64, tile, t);
    } else {                               // W_out^T: grid (16,16)
        const int id = bx - 768;
        const int gx = id & 15, gy = id >> 4;
        tcvt64(Wout, woutt, DIMM, DIMM, gy * 64, gx * 64, tile, t);
    }
}

// ---------------------------------------------------------------------------
// qkv HGEMM 128x192, 4 waves (256 thr), 32x32x16 MFMA, A = x f32 (fused cvt).
// R12: LDS 80 KB -> 2 BLOCKS/CU (vs 1 at 112/128 KB): restores cross-block
// wave overlap (m114 mechanism) so the per-iter barrier drain is hidden by
// the co-resident block — the knob R10/R11 never turned. grid (16,32) = 512
// blocks = 2/CU exactly. Wave grid 2m x 2n: per-wave 64x96, acc[2][3]
// (fragment maps identical to R11). Sync = one-__syncthreads-per-iter dbuf
// (writes->buf[nxt], reads->buf[cur]), proven R4..R11.
// LDS: A bufs 2x16K @ 0/8192, B bufs 2x24K @ 16384/+12288 (f16 offsets).
// Q|K|V col-2048 boundary handled as R11: predicated direct store; blocks
// bx>=10 stage V cols via LDS (48 KB reuse) -> vtg 128B runs.
// Coverage audit (128-key block): stage sidx=rq+4mi+8wm spans 0..15 = all
// 16 key-segs; read-out c<16 spans 0..15; bx=10 stages coll in [128,192).
// ---------------------------------------------------------------------------
__global__ __launch_bounds__(256)
void hgemm256_kernel(const float* __restrict__ X, const _Float16* __restrict__ Bt,
                     const float* __restrict__ bias, _Float16* __restrict__ C,
                     _Float16* __restrict__ vtg, int N, int K)
{
    __shared__ __align__(16) _Float16 lds[40960];   // 80 KB

    const int t    = threadIdx.x;
    const int w    = t >> 6, lane = t & 63;
    const int l31  = lane & 31;
    const int hf   = lane >> 5;
    const int l7   = lane & 7;
    const int wm   = w >> 1;            // 0..1 -> m-offset wm*64
    const int wn   = w & 1;             // 0..1 -> n-offset wn*96
    const int row0 = blockIdx.y * 128, col0 = blockIdx.x * 192;

    f32x16 acc[2][3];
    #pragma unroll
    for (int mi = 0; mi < 2; mi++)
        #pragma unroll
        for (int ni = 0; ni < 3; ni++)
            #pragma unroll
            for (int r = 0; r < 16; r++) acc[mi][ni][r] = 0.f;

    // staging: A 4 16B-segs/thread (1024 segs), B 6 segs/thread (1536 segs)
    const float* gAf[4];
    int aofs[4];
    #pragma unroll
    for (int j = 0; j < 4; j++) {
        const int s   = t + 256 * j;
        const int row = s >> 3;                 // 0..127
        const int kb  = (s & 7) ^ (row & 7);
        gAf[j] = X + (size_t)(row0 + row) * K + kb * 8;
        aofs[j] = s * 8;
    }
    const _Float16* gB[6];
    int bofs[6];
    #pragma unroll
    for (int j = 0; j < 6; j++) {
        const int s   = t + 256 * j;
        const int row = s >> 3;                 // 0..191
        const int kb  = (s & 7) ^ (row & 7);
        gB[j] = Bt + (size_t)(col0 + row) * K + kb * 8;
        bofs[j] = s * 8;
    }

    // prologue: stage tile 0 into buffer 0 (A via regs+cvt, B via DMA)
    {
        float4 pa[4], pb[4];
        #pragma unroll
        for (int j = 0; j < 4; j++) {
            pa[j] = *(const float4*)(gAf[j]);
            pb[j] = *(const float4*)(gAf[j] + 4);
        }
        #pragma unroll
        for (int j = 0; j < 4; j++) *(f16x8*)(lds + aofs[j]) = cvt8(pa[j], pb[j]);
        #pragma unroll
        for (int j = 0; j < 6; j++) gl_lds16(gB[j], lds + 16384 + bofs[j]);
        #pragma unroll
        for (int j = 0; j < 4; j++) gAf[j] += 64;
        #pragma unroll
        for (int j = 0; j < 6; j++) gB[j] += 64;
    }

    const int niter = K >> 6;   // 16
    #pragma unroll 1
    for (int it = 0; it < niter; it++) {
        const int cur = it & 1;
        __syncthreads();        // drains buf[cur] A-writes + B-DMAs; joins buf[cur^1] reads

        float4 pa[4], pb[4];
        const int nxt = cur ^ 1;
        if (it + 1 < niter) {
            #pragma unroll
            for (int j = 0; j < 4; j++) {
                pa[j] = *(const float4*)(gAf[j]);
                pb[j] = *(const float4*)(gAf[j] + 4);
            }
            #pragma unroll
            for (int j = 0; j < 6; j++)
                gl_lds16(gB[j], lds + 16384 + nxt * 12288 + bofs[j]);
            #pragma unroll
            for (int j = 0; j < 4; j++) gAf[j] += 64;
            #pragma unroll
            for (int j = 0; j < 6; j++) gB[j] += 64;
        }

        const _Float16* AsC = lds + cur * 8192;
        const _Float16* BsC = lds + 16384 + cur * 12288;
        #pragma unroll
        for (int ks = 0; ks < 4; ks++) {
            const int pseg = ((ks * 2 + hf) ^ l7) * 8;
            f16x8 bf[3];
            #pragma unroll
            for (int ni = 0; ni < 3; ni++)
                bf[ni] = *(const f16x8*)(BsC + (wn * 96 + ni * 32 + l31) * 64 + pseg);
            #pragma unroll
            for (int mi = 0; mi < 2; mi++) {
                f16x8 af = *(const f16x8*)(AsC + (wm * 64 + mi * 32 + l31) * 64 + pseg);
                #pragma unroll
                for (int ni = 0; ni < 3; ni++)
                    acc[mi][ni] = __builtin_amdgcn_mfma_f32_32x32x16_f16(af, bf[ni], acc[mi][ni], 0, 0, 0);
            }
        }

        if (it + 1 < niter) {
            #pragma unroll
            for (int j = 0; j < 4; j++)
                *(f16x8*)(lds + nxt * 8192 + aofs[j]) = cvt8(pa[j], pb[j]);
        }
    }

    float bv[3];
    #pragma unroll
    for (int ni = 0; ni < 3; ni++) bv[ni] = bias[col0 + wn * 96 + ni * 32 + l31];

    // direct Q/K store (cols < 2048); predicate uniform per (wn,ni) group
    #pragma unroll
    for (int mi = 0; mi < 2; mi++)
        #pragma unroll
        for (int ni = 0; ni < 3; ni++) {
            const int col = col0 + wn * 96 + ni * 32 + l31;
            if (col < 2048) {
                #pragma unroll
                for (int r = 0; r < 16; r++) {
                    const int row = row0 + wm * 64 + mi * 32 + (r & 3) + 8 * (r >> 2) + 4 * hf;
                    C[(size_t)row * N + col] = (_Float16)(acc[mi][ni][r] + bv[ni]);
                }
            }
        }

    if (col0 + 192 <= 2048) return;     // pure Q/K block (bx <= 9)

    // V cols (>= 2048): transpose via LDS -> vtg[bh][d][key], 128B runs.
    __syncthreads();                    // all buf reads done; lds reusable
    // vt stage: [coll 0..191][key_local 0..127] f16 = 48 KB; 16B-seg index
    // along key XOR-swizzled with (coll & 15), same involution both sides.
    #pragma unroll
    for (int mi = 0; mi < 2; mi++)
        #pragma unroll
        for (int ni = 0; ni < 3; ni++) {
            const int coll = wn * 96 + ni * 32 + l31;
            if (col0 + coll >= 2048) {
                #pragma unroll
                for (int rq = 0; rq < 4; rq++) {
                    f16x4 o;
                    #pragma unroll
                    for (int ri = 0; ri < 4; ri++) o[ri] = (_Float16)(acc[mi][ni][rq * 4 + ri] + bv[ni]);
                    const int sidx = rq + 4 * mi + 8 * wm;       // key seg, 0..15
                    *(f16x4*)(lds + coll * 128 + ((sidx ^ (coll & 15)) << 3) + 4 * hf) = o;
                }
            }
        }
    __syncthreads();
    {
        const int cl = t;                   // col_local (use < 192)
        if (cl < 192) {
            const int col = col0 + cl;
            if (col >= 2048) {
                const int head = (col - 2048) >> 6;
                const int dv   = (col - 2048) & 63;
                const int bb   = blockIdx.y >> 4;        // batch (32 row-blocks)
                const int key0 = (blockIdx.y & 15) * 128;
                _Float16* dst = vtg + ((size_t)(bb * 16 + head) * 64 + dv) * SEQ + key0;
                #pragma unroll
                for (int c = 0; c < 16; c++) {           // all 16 key-segs
                    *(f16x8*)(dst + c * 8) = *(const f16x8*)(lds + cl * 128 + ((c ^ (cl & 15)) << 3));
                }
            }
        }
    }
}

// ---------------------------------------------------------------------------
// out-GEMM: 64x128 dbuf pipelined, one __syncthreads per iter. UNCHANGED.
// ---------------------------------------------------------------------------
__global__ __launch_bounds__(256)
void hgemm_out_kernel(const _Float16* __restrict__ A, const _Float16* __restrict__ Bt,
                      const float* __restrict__ bias, float* __restrict__ Cout,
                      int N, int K)
{
    constexpr int BM = 64, MI = 2;
    __shared__ _Float16 As[2][BM * 64];
    __shared__ _Float16 Bs[2][128 * 64];

    const int t    = threadIdx.x;
    const int w    = t >> 6, lane = t & 63;
    const int quad = lane >> 4, l16 = lane & 15;
    const int wr   = w >> 1, wc = w & 1;
    const int row0 = blockIdx.y * BM, col0 = blockIdx.x * 128;
    const int sw   = l16 & 7;

    f32x4 acc[MI][4];
    #pragma unroll
    for (int i = 0; i < MI; i++)
        #pragma unroll
        for (int j = 0; j < 4; j++)
            #pragma unroll
            for (int r = 0; r < 4; r++) acc[i][j][r] = 0.f;

    const _Float16* gA[MI];
    int aofs[MI];
    #pragma unroll
    for (int j = 0; j < MI; j++) {
        const int s   = t + 256 * j;
        const int row = s >> 3;
        const int kb  = (s & 7) ^ (row & 7);
        gA[j] = A + (size_t)(row0 + row) * K + kb * 8;
        aofs[j] = s * 8;
    }
    const _Float16* gB[4];
    int bofs[4];
    #pragma unroll
    for (int j = 0; j < 4; j++) {
        const int s   = t + 256 * j;
        const int row = s >> 3;
        const int kb  = (s & 7) ^ (row & 7);
        gB[j] = Bt + (size_t)(col0 + row) * K + kb * 8;
        bofs[j] = s * 8;
    }

    #pragma unroll
    for (int j = 0; j < MI; j++) gl_lds16(gA[j], &As[0][aofs[j]]);
    #pragma unroll
    for (int j = 0; j < 4; j++)  gl_lds16(gB[j], &Bs[0][bofs[j]]);
    #pragma unroll
    for (int j = 0; j < MI; j++) gA[j] += 64;
    #pragma unroll
    for (int j = 0; j < 4; j++)  gB[j] += 64;

    const int niter = K >> 6;
    #pragma unroll 1
    for (int it = 0; it < niter; it++) {
        const int cur = it & 1;
        __syncthreads();

        if (it + 1 < niter) {
            const int nxt = cur ^ 1;
            #pragma unroll
            for (int j = 0; j < MI; j++) gl_lds16(gA[j], &As[nxt][aofs[j]]);
            #pragma unroll
            for (int j = 0; j < 4; j++)  gl_lds16(gB[j], &Bs[nxt][bofs[j]]);
            #pragma unroll
            for (int j = 0; j < MI; j++) gA[j] += 64;
            #pragma unroll
            for (int j = 0; j < 4; j++)  gB[j] += 64;
        }

        const _Float16* AsC = &As[cur][0];
        const _Float16* BsC = &Bs[cur][0];
        f16x8 af[MI][2], bf[4][2];
        #pragma unroll
        for (int i = 0; i < MI; i++) {
            const int arow = wr * (BM / 2) + i * 16 + l16;
            #pragma unroll
            for (int hh = 0; hh < 2; hh++)
                af[i][hh] = *(const f16x8*)(AsC + (arow * 8 + ((hh * 4 + quad) ^ sw)) * 8);
        }
        #pragma unroll
        for (int j = 0; j < 4; j++) {
            const int brow = wc * 64 + j * 16 + l16;
            #pragma unroll
            for (int hh = 0; hh < 2; hh++)
                bf[j][hh] = *(const f16x8*)(BsC + (brow * 8 + ((hh * 4 + quad) ^ sw)) * 8);
        }
        #pragma unroll
        for (int i = 0; i < MI; i++)
            #pragma unroll
            for (int j = 0; j < 4; j++) {
                acc[i][j] = __builtin_amdgcn_mfma_f32_16x16x32_f16(af[i][0], bf[j][0], acc[i][j], 0, 0, 0);
                acc[i][j] = __builtin_amdgcn_mfma_f32_16x16x32_f16(af[i][1], bf[j][1], acc[i][j], 0, 0, 0);
            }
    }

    #pragma unroll
    for (int j = 0; j < 4; j++) {
        const int col = col0 + wc * 64 + j * 16 + l16;
        const float bv = bias[col];
        #pragma unroll
        for (int i = 0; i < MI; i++) {
            const int row = row0 + wr * (BM / 2) + i * 16 + quad * 4;
            #pragma unroll
            for (int r = 0; r < 4; r++)
                Cout[(size_t)(row + r) * N + col] = acc[i][j][r] + bv;
        }
    }
}

// ---------------------------------------------------------------------------
// MFMA flash attention — UNCHANGED from round 10/11 (52-53 µs, absmax
// 4.88e-4): in-register P (32x32x16), ONE __syncthreads per tile,
// XCD-clustered swizzle, 1-mul exp, setprio, fdot2 denominator.
// ---------------------------------------------------------------------------
__global__ __launch_bounds__(256, 4)
void flash_attn_kernel(const _Float16* __restrict__ qkv,
                       const _Float16* __restrict__ vtg,
                       _Float16* __restrict__ out)
{
    const int lin = blockIdx.y * 32 + blockIdx.x;   // 0..1023
    const int bh  = (lin & 7) * 4 + (lin >> 8);     // 0..31
    const int qt  = (lin >> 3) & 31;                // 0..31
    const int b  = bh >> 4, hd = bh & 15;
    const int t    = threadIdx.x;
    const int w    = t >> 6;
    const int lane = t & 63;
    const int qg   = w >> 1;            // q-group (32 rows)
    const int kh   = w & 1;             // key-half (32 keys)
    const int l31  = lane & 31;
    const int hf   = lane >> 5;         // lane half
    const int l7   = lane & 7;

    __shared__ __align__(16) _Float16 Ks [2][64 * 64];
    __shared__ __align__(16) _Float16 Vts[2][64 * 64];

    const int q0 = qt * 64;
    const size_t rstr = 3 * DIMM;
    const _Float16* qbase = qkv + (size_t)b * SEQ * rstr;

    f16x8 qf[4];
    {
        const _Float16* qrow = qbase + (size_t)(q0 + qg * 32 + l31) * rstr + hd * HDIM;
        #pragma unroll
        for (int dd = 0; dd < 4; dd++)
            qf[dd] = *(const f16x8*)(qrow + dd * 16 + hf * 8);
    }

    f32x16 Oacc[2];
    #pragma unroll
    for (int dh = 0; dh < 2; dh++)
        #pragma unroll
        for (int r = 0; r < 16; r++) Oacc[dh][r] = 0.f;
    float lrow = 0.f;
    const h2 k1 = {(_Float16)1.f, (_Float16)1.f};

    const int seg0 = t, seg1 = t + 256;
    const int r0 = seg0 >> 3, lb0 = (seg0 & 7) ^ (r0 & 7);
    const int r1 = seg1 >> 3, lb1 = (seg1 & 7) ^ (r1 & 7);
    const _Float16* gK0 = qbase + (size_t)r0 * rstr + DIMM + hd * HDIM + lb0 * 8;
    const _Float16* gK1 = qbase + (size_t)r1 * rstr + DIMM + hd * HDIM + lb1 * 8;
    const _Float16* gV0 = vtg + ((size_t)bh * 64 + r0) * SEQ + lb0 * 8;
    const _Float16* gV1 = vtg + ((size_t)bh * 64 + r1) * SEQ + lb1 * 8;

    gl_lds16(gK0, &Ks [0][seg0 * 8]);
    gl_lds16(gK1, &Ks [0][seg1 * 8]);
    gl_lds16(gV0, &Vts[0][seg0 * 8]);
    gl_lds16(gV1, &Vts[0][seg1 * 8]);

    #pragma unroll 2
    for (int k0 = 0; k0 < SEQ; k0 += 64) {
        const int cur = (k0 >> 6) & 1;
        const _Float16* KsC  = &Ks [cur][0];
        const _Float16* VtsC = &Vts[cur][0];

        __syncthreads();

        f32x16 sacc;
        #pragma unroll
        for (int r = 0; r < 16; r++) sacc[r] = 0.f;
        __builtin_amdgcn_s_setprio(1);
        #pragma unroll
        for (int dd = 0; dd < 4; dd++) {
            f16x8 kf = *(const f16x8*)(KsC + (kh * 32 + l31) * 64 + (((dd * 2 + hf) ^ l7) * 8));
            sacc = __builtin_amdgcn_mfma_f32_32x32x16_f16(kf, qf[dd], sacc, 0, 0, 0);
        }
        __builtin_amdgcn_s_setprio(0);

        if (k0 + 64 < SEQ) {
            const int nxt = cur ^ 1;
            gl_lds16(gK0 + (size_t)(k0 + 64) * rstr, &Ks [nxt][seg0 * 8]);
            gl_lds16(gK1 + (size_t)(k0 + 64) * rstr, &Ks [nxt][seg1 * 8]);
            gl_lds16(gV0 + (k0 + 64),                &Vts[nxt][seg0 * 8]);
            gl_lds16(gV1 + (k0 + 64),                &Vts[nxt][seg1 * 8]);
        }

        float e[16];
        #pragma unroll
        for (int r = 0; r < 16; r++) {
            const float xx = sacc[r] * 0.18033688011112042f;   // 0.125*log2(e)
            float ee;
            asm("v_exp_f32 %0, %1" : "=v"(ee) : "v"(xx));
            e[r] = ee;
        }

        unsigned w01 = __builtin_bit_cast(unsigned, __builtin_amdgcn_cvt_pkrtz(e[0],  e[1]));
        unsigned w23 = __builtin_bit_cast(unsigned, __builtin_amdgcn_cvt_pkrtz(e[2],  e[3]));
        unsigned w45 = __builtin_bit_cast(unsigned, __builtin_amdgcn_cvt_pkrtz(e[4],  e[5]));
        unsigned w67 = __builtin_bit_cast(unsigned, __builtin_amdgcn_cvt_pkrtz(e[6],  e[7]));
        unsigned w89 = __builtin_bit_cast(unsigned, __builtin_amdgcn_cvt_pkrtz(e[8],  e[9]));
        unsigned wab = __builtin_bit_cast(unsigned, __builtin_amdgcn_cvt_pkrtz(e[10], e[11]));
        unsigned wcd = __builtin_bit_cast(unsigned, __builtin_amdgcn_cvt_pkrtz(e[12], e[13]));
        unsigned wef = __builtin_bit_cast(unsigned, __builtin_amdgcn_cvt_pkrtz(e[14], e[15]));

        lrow = __builtin_amdgcn_fdot2(__builtin_bit_cast(h2, w01), k1, lrow, false);
        lrow = __builtin_amdgcn_fdot2(__builtin_bit_cast(h2, w23), k1, lrow, false);
        lrow = __builtin_amdgcn_fdot2(__builtin_bit_cast(h2, w45), k1, lrow, false);
        lrow = __builtin_amdgcn_fdot2(__builtin_bit_cast(h2, w67), k1, lrow, false);
        lrow = __builtin_amdgcn_fdot2(__builtin_bit_cast(h2, w89), k1, lrow, false);
        lrow = __builtin_amdgcn_fdot2(__builtin_bit_cast(h2, wab), k1, lrow, false);
        lrow = __builtin_amdgcn_fdot2(__builtin_bit_cast(h2, wcd), k1, lrow, false);
        lrow = __builtin_amdgcn_fdot2(__builtin_bit_cast(h2, wef), k1, lrow, false);

        unsigned p00 = w01, p02 = w45;
        asm("v_permlane32_swap_b32 %0, %1" : "+v"(p00), "+v"(p02));
        unsigned p01 = w23, p03 = w67;
        asm("v_permlane32_swap_b32 %0, %1" : "+v"(p01), "+v"(p03));
        unsigned p10 = w89, p12 = wcd;
        asm("v_permlane32_swap_b32 %0, %1" : "+v"(p10), "+v"(p12));
        unsigned p11 = wab, p13 = wef;
        asm("v_permlane32_swap_b32 %0, %1" : "+v"(p11), "+v"(p13));
        f16x8 pa0 = mkfrag(p00, p01, p02, p03);
        f16x8 pa1 = mkfrag(p10, p11, p12, p13);

        __builtin_amdgcn_s_setprio(1);
        #pragma unroll
        for (int dh = 0; dh < 2; dh++) {
            const _Float16* vrow = VtsC + (dh * 32 + l31) * 64;
            f16x8 vf0 = *(const f16x8*)(vrow + (((kh * 4 + 0 + hf) ^ l7) * 8));
            f16x8 vf1 = *(const f16x8*)(vrow + (((kh * 4 + 2 + hf) ^ l7) * 8));
            Oacc[dh] = __builtin_amdgcn_mfma_f32_32x32x16_f16(pa0, vf0, Oacc[dh], 0, 0, 0);
            Oacc[dh] = __builtin_amdgcn_mfma_f32_32x32x16_f16(pa1, vf1, Oacc[dh], 0, 0, 0);
        }
        __builtin_amdgcn_s_setprio(0);
    }

    float lsum = lrow + __shfl_xor(lrow, 32);
    __syncthreads();
    float* Obuf = (float*)&Ks[0][0];
    float* lbuf = (float*)&Vts[0][0];
    if (kh) {
        #pragma unroll
        for (int dh = 0; dh < 2; dh++)
            #pragma unroll
            for (int r = 0; r < 16; r++) {
                const int q = (r & 3) + 8 * (r >> 2) + 4 * hf;
                Obuf[(qg * 32 + q) * 64 + dh * 32 + l31] = Oacc[dh][r];
            }
        if (lane < 32) lbuf[qg * 32 + lane] = lsum;
    }
    __syncthreads();
    if (!kh) {
        const float dnrec = 1.f / (lsum + lbuf[qg * 32 + l31]);
        float dq[16];
        #pragma unroll
        for (int r = 0; r < 16; r++)
            dq[r] = __shfl(dnrec, (r & 3) + 8 * (r >> 2) + 4 * hf);
        #pragma unroll
        for (int dh = 0; dh < 2; dh++)
            #pragma unroll
            for (int r = 0; r < 16; r++) {
                const int q = (r & 3) + 8 * (r >> 2) + 4 * hf;
                const float v = (Oacc[dh][r] + Obuf[(qg * 32 + q) * 64 + dh * 32 + l31])
                                * dq[r];
                out[(size_t)(b * SEQ + q0 + qg * 32 + q) * DIMM + hd * HDIM + dh * 32 + l31] =
                    (_Float16)v;
            }
    }
}

// ---------------------------------------------------------------------------
extern "C" void kernel_launch(void* const* d_in, const int* in_sizes, int n_in,
                              void* d_out, int out_size, void* d_ws, size_t ws_size,
                              hipStream_t stream)
{
    const float* x    = (const float*)d_in[0];   // [2,2048,1024]
    const float* Wqkv = (const float*)d_in[1];   // [1024,3072]
    const float* bqkv = (const float*)d_in[2];   // [3072]
    const float* Wout = (const float*)d_in[3];   // [1024,1024]
    const float* bout = (const float*)d_in[4];   // [1024]
    float* out = (float*)d_out;                  // [2,2048,1024]

    _Float16* qkvh  = (_Float16*)d_ws;                   // 4096x3072 (V-third unused)
    _Float16* attnh = qkvh  + (size_t)ROWS * 3 * DIMM;   // 4096x1024
    _Float16* xh    = attnh + (size_t)ROWS * DIMM;       // 4096x1024 (unused now)
    _Float16* wqkvt = xh    + (size_t)ROWS * DIMM;       // 3072x1024
    _Float16* woutt = wqkvt + (size_t)3 * DIMM * DIMM;   // 1024x1024
    _Float16* vtg   = woutt + (size_t)DIMM * DIMM;       // 32 x 64 x 2048

    // 0) weight transposes only
    prep_kernel<<<1024, 256, 0, stream>>>(Wqkv, Wout, wqkvt, woutt);
    // 1) qkv = x @ W_qkv + b_qkv (A = x f32, fused cvt); 128x192 tiles,
    //    grid (16,32) = 512 blocks = 2/CU (cross-block overlap restored);
    //    V cols -> vtg transposed
    {
        dim3 grid(3 * DIMM / 192, ROWS / 128);   // (16,32)
        hgemm256_kernel<<<grid, 256, 0, stream>>>(x, wqkvt, bqkv, qkvh, vtg, 3 * DIMM, DIMM);
    }
    // 2) attention -> attnh (fp16)
    {
        dim3 grid(SEQ / 64, BATCH * NHEADS);
        flash_attn_kernel<<<grid, 256, 0, stream>>>(qkvh, vtg, attnh);
    }
    // 3) out = attn @ W_out + b_out (fp32) — 64x128 dbuf, 512 blocks
    {
        dim3 grid(DIMM / 128, ROWS / 64);
        hgemm_out_kernel<<<grid, 256, 0, stream>>>(attnh, woutt, bout, out, DIMM, DIMM);
    }
}